// Round 6
// baseline (526.547 us; speedup 1.0000x reference)
//
#include <hip/hip_runtime.h>

typedef unsigned short ushort_t;
typedef unsigned int uint_t;

typedef __bf16 bf16x8 __attribute__((ext_vector_type(8)));
typedef float f32x4 __attribute__((ext_vector_type(4)));

static __device__ __forceinline__ float bf2f(ushort_t h) {
    return __uint_as_float(((uint_t)h) << 16);
}
static __device__ __forceinline__ ushort_t f2bf(float f) {
    uint_t u = __float_as_uint(f);
    u = u + 0x7FFFu + ((u >> 16) & 1u);
    return (ushort_t)(u >> 16);
}
// pack two floats as bf16 (round-half-up) into one dword: low=lo, high=hi
static __device__ __forceinline__ uint_t pkbf(float lo, float hi) {
    uint_t a = __float_as_uint(lo) + 0x8000u;
    uint_t b = __float_as_uint(hi) + 0x8000u;
    return __builtin_amdgcn_perm(b, a, 0x07060302u);
}

// ---------------- constants ----------------
#define BB 32
#define HH 56
#define WW_ 56
#define CC 128
#define NHEAD 4
#define WS 7
#define SS 3
#define LL (HH * WW_)           // 3136
#define NTOK (BB * LL)          // 100352
#define NWIN (BB * 64)          // 2048
#define NN 49
#define HD 32

// windowed token -> global token (shift map)
static __device__ __forceinline__ int win2tok(int wid) {
    int win = wid / NN, t = wid - win * NN;
    int bb = win >> 6, wrem = win & 63;
    int wi = wrem >> 3, wj = wrem & 7;
    int ti = t / WS, tj = t - ti * WS;
    int hh = wi * WS + ti + SS; if (hh >= HH) hh -= HH;
    int ww = wj * WS + tj + SS; if (ww >= WW_) ww -= WW_;
    return bb * LL + hh * WW_ + ww;
}

// ============ weight pre-convert fp32->bf16 ============
__global__ __launch_bounds__(256) void prep_weights(
    const float* __restrict__ qkv_w, const float* __restrict__ proj_w,
    const float* __restrict__ fc1_w, const float* __restrict__ fc2_w,
    ushort_t* __restrict__ dst) {
    int i = blockIdx.x * 256 + threadIdx.x;   // 0 .. 196607
    const float* src;
    int off;
    if (i < 49152)        { src = qkv_w;  off = i; }
    else if (i < 65536)   { src = proj_w; off = i - 49152; }
    else if (i < 131072)  { src = fc1_w;  off = i - 65536; }
    else                  { src = fc2_w;  off = i - 131072; }
    dst[i] = f2bf(src[off]);
}

// ============ bias table: bias[h][i][j] (64x64 padded, fp32) ============
__global__ __launch_bounds__(256) void build_bias(
    const float* __restrict__ rpb, const int* __restrict__ rel_idx,
    float* __restrict__ bias) {
    int h = blockIdx.x;
    for (int idx = threadIdx.x; idx < 4096; idx += 256) {
        int i = idx >> 6, j = idx & 63;
        float v = 0.f;
        if (i < NN && j < NN)
            v = rpb[(size_t)rel_idx[i * NN + j] * NHEAD + h];
        bias[h * 4096 + idx] = v;
    }
}

// ============ K1: fused LN1+shift+window + QKV GEMM (swapped C-write) ============
__global__ __launch_bounds__(256) void qkv_fused(
    const float* __restrict__ x, const float* __restrict__ g1,
    const float* __restrict__ b1, const ushort_t* __restrict__ wq,
    const float* __restrict__ qkv_b, ushort_t* __restrict__ qkv,
    int wid0) {
    __shared__ __align__(16) ushort_t As[128 * 136];
    const int tid = threadIdx.x;
    const int m0 = blockIdx.x * 128;
    const int wave = tid >> 6;
    const int lane = tid & 63;
    const int l16 = lane & 15;
    const int quad = lane >> 4;
    const int wm = (wave & 1) * 64;
    const int wn = (wave >> 1) * 64;

    // ---- prologue: LN1 over shifted source rows ----
    {
        int row = tid >> 1;
        int half = (tid & 1) * 64;
        int gtok = win2tok(wid0 + m0 + row);
        const float* xp = x + (size_t)gtok * CC + half;
        float v[64];
        float s = 0.f, sq = 0.f;
        #pragma unroll
        for (int i = 0; i < 16; ++i) {
            float4 a = *(const float4*)(xp + i * 4);
            v[i * 4 + 0] = a.x; v[i * 4 + 1] = a.y;
            v[i * 4 + 2] = a.z; v[i * 4 + 3] = a.w;
            s += a.x + a.y + a.z + a.w;
            sq += a.x * a.x + a.y * a.y + a.z * a.z + a.w * a.w;
        }
        s += __shfl_xor(s, 1);
        sq += __shfl_xor(sq, 1);
        float mean = s * (1.0f / 128.0f);
        float var = sq * (1.0f / 128.0f) - mean * mean;
        float rstd = rsqrtf(var + 1e-5f);
        #pragma unroll
        for (int i = 0; i < 8; ++i) {
            ushort_t tmp[8];
            #pragma unroll
            for (int j = 0; j < 8; ++j) {
                int c = half + i * 8 + j;
                tmp[j] = f2bf((v[i * 8 + j] - mean) * rstd * g1[c] + b1[c]);
            }
            *(uint4*)&As[row * 136 + half + i * 8] = *(const uint4*)tmp;
        }
    }
    __syncthreads();

    // ---- 3 N-chunks of 128 cols; mfma(W as A, tokens as B) -> D^T ----
    for (int nc = 0; nc < 3; ++nc) {
        f32x4 acc[4][4];   // [j colTile][i tokTile]
        #pragma unroll
        for (int j = 0; j < 4; ++j)
            #pragma unroll
            for (int i = 0; i < 4; ++i)
                acc[j][i] = (f32x4){0.f, 0.f, 0.f, 0.f};
        #pragma unroll
        for (int kk = 0; kk < 4; ++kk) {
            bf16x8 tf[4];
            #pragma unroll
            for (int i = 0; i < 4; ++i)
                tf[i] = *(const bf16x8*)&As[(wm + 16 * i + l16) * 136 + kk * 32 + quad * 8];
            #pragma unroll
            for (int j = 0; j < 4; ++j) {
                bf16x8 wf = *(const bf16x8*)&wq[(size_t)(nc * 128 + wn + 16 * j + l16) * 128 + kk * 32 + quad * 8];
                #pragma unroll
                for (int i = 0; i < 4; ++i)
                    acc[j][i] = __builtin_amdgcn_mfma_f32_16x16x32_bf16(wf, tf[i], acc[j][i], 0, 0, 0);
            }
        }
        // C/D of D^T: qkvcol = wn+16j+quad*4+r, token = wm+16i+l16 -> 8B stores
        #pragma unroll
        for (int j = 0; j < 4; ++j) {
            float4 bv = *(const float4*)&qkv_b[nc * 128 + wn + 16 * j + quad * 4];
            #pragma unroll
            for (int i = 0; i < 4; ++i) {
                int token = m0 + wm + 16 * i + l16;
                uint2 pk;
                pk.x = pkbf(acc[j][i][0] + bv.x, acc[j][i][1] + bv.y);
                pk.y = pkbf(acc[j][i][2] + bv.z, acc[j][i][3] + bv.w);
                *(uint2*)&qkv[(size_t)token * 384 + nc * 128 + wn + 16 * j + quad * 4] = pk;
            }
        }
    }
}

// ============ K2: MFMA windowed attention (verified r3-r5, unchanged) ============
__global__ __launch_bounds__(256) void attn_mfma(
    const ushort_t* __restrict__ qkv, const float* __restrict__ bias,
    ushort_t* __restrict__ attn_out) {
    __shared__ __align__(16) ushort_t Vt[NHEAD][32 * 72];
    __shared__ __align__(16) ushort_t Ps[NHEAD][64 * 72];
    const int tid = threadIdx.x;
    const int wave = tid >> 6;
    const int lane = tid & 63;
    const int l16 = lane & 15;
    const int quad = lane >> 4;
    const int win = blockIdx.x;
    const int h = wave;
    const float scale = 0.17677669529663687f;

    ushort_t* vt = Vt[wave];
    ushort_t* ps = Ps[wave];

    {
        int r0 = lane >> 2;
        int dc = (lane & 3) * 8;
        #pragma unroll
        for (int pass = 0; pass < 4; ++pass) {
            int i = pass * 16 + r0;
            if (i < NN) {
                const ushort_t* src = &qkv[((size_t)(win * NN + i)) * 384 + 256 + h * HD + dc];
                ushort4 a = *(const ushort4*)src;
                ushort4 b = *(const ushort4*)(src + 4);
                vt[(dc + 0) * 72 + i] = a.x; vt[(dc + 1) * 72 + i] = a.y;
                vt[(dc + 2) * 72 + i] = a.z; vt[(dc + 3) * 72 + i] = a.w;
                vt[(dc + 4) * 72 + i] = b.x; vt[(dc + 5) * 72 + i] = b.y;
                vt[(dc + 6) * 72 + i] = b.z; vt[(dc + 7) * 72 + i] = b.w;
            }
        }
        #pragma unroll
        for (int j = 0; j < 8; ++j) {
            int idx = lane * 8 + j;
            if (idx < 32 * 15) {
                int d = idx / 15, n = NN + idx - d * 15;
                vt[d * 72 + n] = 0;
            }
        }
    }

    f32x4 s[4][4];
    {
        bf16x8 qa[4], kb[4];
        #pragma unroll
        for (int t = 0; t < 4; ++t) {
            size_t rb = ((size_t)(win * NN + 16 * t + l16)) * 384 + h * HD + quad * 8;
            qa[t] = *(const bf16x8*)&qkv[rb];
            kb[t] = *(const bf16x8*)&qkv[rb + 128];
        }
        #pragma unroll
        for (int mi = 0; mi < 4; ++mi)
            #pragma unroll
            for (int ni = 0; ni < 4; ++ni) {
                f32x4 z = {0.f, 0.f, 0.f, 0.f};
                s[mi][ni] = __builtin_amdgcn_mfma_f32_16x16x32_bf16(qa[mi], kb[ni], z, 0, 0, 0);
            }
    }

    const float* bh = bias + h * 4096;
    #pragma unroll
    for (int mi = 0; mi < 4; ++mi)
        #pragma unroll
        for (int ni = 0; ni < 4; ++ni)
            #pragma unroll
            for (int r = 0; r < 4; ++r)
                s[mi][ni][r] = s[mi][ni][r] * scale +
                               bh[(16 * mi + quad * 4 + r) * 64 + 16 * ni + l16];

    #pragma unroll
    for (int mi = 0; mi < 4; ++mi)
        #pragma unroll
        for (int r = 0; r < 4; ++r) {
            float m01 = fmaxf(s[mi][0][r], s[mi][1][r]);
            float m2 = s[mi][2][r];
            float m3 = (l16 == 0) ? s[mi][3][r] : -3.0e38f;
            float mx = fmaxf(fmaxf(m01, m2), m3);
            mx = fmaxf(mx, __shfl_xor(mx, 1));
            mx = fmaxf(mx, __shfl_xor(mx, 2));
            mx = fmaxf(mx, __shfl_xor(mx, 4));
            mx = fmaxf(mx, __shfl_xor(mx, 8));
            float e0 = expf(s[mi][0][r] - mx);
            float e1 = expf(s[mi][1][r] - mx);
            float e2 = expf(s[mi][2][r] - mx);
            float e3 = (l16 == 0) ? expf(s[mi][3][r] - mx) : 0.f;
            float sum = (e0 + e1) + (e2 + e3);
            sum += __shfl_xor(sum, 1);
            sum += __shfl_xor(sum, 2);
            sum += __shfl_xor(sum, 4);
            sum += __shfl_xor(sum, 8);
            float inv = 1.0f / sum;
            s[mi][0][r] = e0 * inv;
            s[mi][1][r] = e1 * inv;
            s[mi][2][r] = e2 * inv;
            s[mi][3][r] = e3 * inv;
        }

    #pragma unroll
    for (int mi = 0; mi < 4; ++mi)
        #pragma unroll
        for (int ni = 0; ni < 4; ++ni)
            #pragma unroll
            for (int r = 0; r < 4; ++r)
                ps[(16 * mi + quad * 4 + r) * 72 + 16 * ni + l16] = f2bf(s[mi][ni][r]);

    f32x4 o[2][4];
    #pragma unroll
    for (int it = 0; it < 2; ++it)
        #pragma unroll
        for (int jt = 0; jt < 4; ++jt)
            o[it][jt] = (f32x4){0.f, 0.f, 0.f, 0.f};
    #pragma unroll
    for (int k0 = 0; k0 < 64; k0 += 32) {
        bf16x8 va[2], pb[4];
        #pragma unroll
        for (int it = 0; it < 2; ++it)
            va[it] = *(const bf16x8*)&vt[(16 * it + l16) * 72 + k0 + quad * 8];
        #pragma unroll
        for (int jt = 0; jt < 4; ++jt)
            pb[jt] = *(const bf16x8*)&ps[(16 * jt + l16) * 72 + k0 + quad * 8];
        #pragma unroll
        for (int it = 0; it < 2; ++it)
            #pragma unroll
            for (int jt = 0; jt < 4; ++jt)
                o[it][jt] = __builtin_amdgcn_mfma_f32_16x16x32_bf16(va[it], pb[jt], o[it][jt], 0, 0, 0);
    }

    #pragma unroll
    for (int jt = 0; jt < 4; ++jt) {
        int m = 16 * jt + l16;
        if (m < NN) {
            #pragma unroll
            for (int it = 0; it < 2; ++it) {
                ushort4 st;
                st.x = f2bf(o[it][jt][0]);
                st.y = f2bf(o[it][jt][1]);
                st.z = f2bf(o[it][jt][2]);
                st.w = f2bf(o[it][jt][3]);
                *(ushort4*)&attn_out[((size_t)(win * NN + m)) * CC + h * HD + 16 * it + quad * 4] = st;
            }
        }
    }
}

// ============ K3: fused proj GEMM + window-reverse + residual + LN2 ============
__global__ __launch_bounds__(256) void proj_fused(
    const ushort_t* __restrict__ attn, const ushort_t* __restrict__ wp,
    const float* __restrict__ proj_b, const float* __restrict__ x,
    const float* __restrict__ g2, const float* __restrict__ b2,
    float* __restrict__ out, ushort_t* __restrict__ h2buf, int wid0) {
    __shared__ __align__(16) ushort_t As[64 * 136];
    __shared__ __align__(16) ushort_t PS[64 * 136];
    const int tid = threadIdx.x;
    const int m0 = blockIdx.x * 64;
    const int wave = tid >> 6;
    const int lane = tid & 63;
    const int l16 = lane & 15;
    const int quad = lane >> 4;
    const int wn = wave * 32;

    #pragma unroll
    for (int u = tid; u < 1024; u += 256) {
        int row = u >> 4, ch = (u & 15) * 8;
        *(uint4*)&As[row * 136 + ch] = *(const uint4*)&attn[(size_t)(m0 + row) * CC + ch];
    }
    __syncthreads();

    f32x4 acc[2][4];   // [j projColTile][i tokTile]
    #pragma unroll
    for (int j = 0; j < 2; ++j)
        #pragma unroll
        for (int i = 0; i < 4; ++i)
            acc[j][i] = (f32x4){0.f, 0.f, 0.f, 0.f};
    #pragma unroll
    for (int kk = 0; kk < 4; ++kk) {
        bf16x8 tf[4];
        #pragma unroll
        for (int i = 0; i < 4; ++i)
            tf[i] = *(const bf16x8*)&As[(16 * i + l16) * 136 + kk * 32 + quad * 8];
        #pragma unroll
        for (int j = 0; j < 2; ++j) {
            bf16x8 wf = *(const bf16x8*)&wp[(size_t)(wn + 16 * j + l16) * 128 + kk * 32 + quad * 8];
            #pragma unroll
            for (int i = 0; i < 4; ++i)
                acc[j][i] = __builtin_amdgcn_mfma_f32_16x16x32_bf16(wf, tf[i], acc[j][i], 0, 0, 0);
        }
    }
    // D^T: projcol = wn+16j+quad*4+r, token = 16i+l16 -> b64 LDS stores
    #pragma unroll
    for (int j = 0; j < 2; ++j) {
        float4 bv = *(const float4*)&proj_b[wn + 16 * j + quad * 4];
        #pragma unroll
        for (int i = 0; i < 4; ++i) {
            uint2 pk;
            pk.x = pkbf(acc[j][i][0] + bv.x, acc[j][i][1] + bv.y);
            pk.y = pkbf(acc[j][i][2] + bv.z, acc[j][i][3] + bv.w);
            *(uint2*)&PS[(16 * i + l16) * 136 + wn + 16 * j + quad * 4] = pk;
        }
    }
    __syncthreads();

    // epilogue: residual + LN2, scatter to global order
    {
        int row = tid >> 2;
        int ch0 = (tid & 3) * 32;
        int gtok = win2tok(wid0 + m0 + row);
        const float* xp = x + (size_t)gtok * CC + ch0;
        float v[32];
        float s = 0.f, sq = 0.f;
        #pragma unroll
        for (int i = 0; i < 4; ++i) {
            float4 a0 = *(const float4*)(xp + i * 8);
            float4 a1 = *(const float4*)(xp + i * 8 + 4);
            ushort4 p0 = *(const ushort4*)&PS[row * 136 + ch0 + i * 8];
            ushort4 p1 = *(const ushort4*)&PS[row * 136 + ch0 + i * 8 + 4];
            v[i * 8 + 0] = a0.x + bf2f(p0.x); v[i * 8 + 1] = a0.y + bf2f(p0.y);
            v[i * 8 + 2] = a0.z + bf2f(p0.z); v[i * 8 + 3] = a0.w + bf2f(p0.w);
            v[i * 8 + 4] = a1.x + bf2f(p1.x); v[i * 8 + 5] = a1.y + bf2f(p1.y);
            v[i * 8 + 6] = a1.z + bf2f(p1.z); v[i * 8 + 7] = a1.w + bf2f(p1.w);
            #pragma unroll
            for (int j = 0; j < 8; ++j) { s += v[i * 8 + j]; sq += v[i * 8 + j] * v[i * 8 + j]; }
        }
        float* op = out + (size_t)gtok * CC + ch0;
        #pragma unroll
        for (int i = 0; i < 8; ++i)
            *(float4*)(op + i * 4) = *(const float4*)(v + i * 4);
        s += __shfl_xor(s, 1);  sq += __shfl_xor(sq, 1);
        s += __shfl_xor(s, 2);  sq += __shfl_xor(sq, 2);
        float mean = s * (1.0f / 128.0f);
        float var = sq * (1.0f / 128.0f) - mean * mean;
        float rstd = rsqrtf(var + 1e-5f);
        #pragma unroll
        for (int i = 0; i < 4; ++i) {
            ushort_t tmp[8];
            #pragma unroll
            for (int j = 0; j < 8; ++j) {
                int c = ch0 + i * 8 + j;
                tmp[j] = f2bf((v[i * 8 + j] - mean) * rstd * g2[c] + b2[c]);
            }
            *(uint4*)&h2buf[(size_t)gtok * CC + ch0 + i * 8] = *(const uint4*)tmp;
        }
    }
}

// ============ K4: wave-private fc1+GELU+fc2, zero barriers ============
// Block = 64 tokens, wave owns 16. H2 A-frags cached in regs from global.
// MFMA1 swapped (D=W1c·H2^T) -> P via 8 ds_write_b64/chunk into private LDS;
// MFMA2 swapped (Y^T=W2c·P^T) -> epilogue 8 float4 RMWs.
__global__ __launch_bounds__(256) void mlp2(
    const ushort_t* __restrict__ h2, const ushort_t* __restrict__ w1,
    const float* __restrict__ b1, const ushort_t* __restrict__ w2,
    const float* __restrict__ bias2, float* __restrict__ out) {
    __shared__ __align__(16) ushort_t PS[4][16 * 136];
    const int tid = threadIdx.x;
    const int wave = tid >> 6;
    const int lane = tid & 63;
    const int l16 = lane & 15;
    const int quad = lane >> 4;
    const int tok = blockIdx.x * 64 + wave * 16 + l16;
    ushort_t* ps = PS[wave];

    bf16x8 hf[4];
    #pragma unroll
    for (int kk = 0; kk < 4; ++kk)
        hf[kk] = *(const bf16x8*)&h2[(size_t)tok * CC + kk * 32 + quad * 8];

    f32x4 acc2[8];
    #pragma unroll
    for (int j = 0; j < 8; ++j) acc2[j] = (f32x4){0.f, 0.f, 0.f, 0.f};

    for (int c = 0; c < 4; ++c) {
        // MFMA1: D = W1c · H2^T  (fc1col = 16j+quad*4+r, token = l16)
        f32x4 s1[8];
        #pragma unroll
        for (int j = 0; j < 8; ++j) s1[j] = (f32x4){0.f, 0.f, 0.f, 0.f};
        #pragma unroll
        for (int kk = 0; kk < 4; ++kk) {
            #pragma unroll
            for (int j = 0; j < 8; ++j) {
                bf16x8 wf = *(const bf16x8*)&w1[(size_t)(c * 128 + j * 16 + l16) * 128 + kk * 32 + quad * 8];
                s1[j] = __builtin_amdgcn_mfma_f32_16x16x32_bf16(wf, hf[kk], s1[j], 0, 0, 0);
            }
        }
        // bias + GELU + pack -> private PS[token=l16][fc1col]
        #pragma unroll
        for (int j = 0; j < 8; ++j) {
            float4 bv = *(const float4*)&b1[c * 128 + j * 16 + quad * 4];
            float g[4];
            #pragma unroll
            for (int r = 0; r < 4; ++r) {
                float u = s1[j][r] + ((const float*)&bv)[r];
                float z = 1.5957691216f * u * (1.0f + 0.044715f * u * u);
                g[r] = u / (1.0f + __expf(-z));
            }
            uint2 pk;
            pk.x = pkbf(g[0], g[1]);
            pk.y = pkbf(g[2], g[3]);
            *(uint2*)&ps[l16 * 136 + j * 16 + quad * 4] = pk;
        }
        // MFMA2: Y^T += W2c · P^T  (outcol = 16j+quad*4+r, token = l16)
        #pragma unroll
        for (int kk = 0; kk < 4; ++kk) {
            bf16x8 pf = *(const bf16x8*)&ps[l16 * 136 + kk * 32 + quad * 8];
            #pragma unroll
            for (int j = 0; j < 8; ++j) {
                bf16x8 wf = *(const bf16x8*)&w2[(size_t)(j * 16 + l16) * 512 + c * 128 + kk * 32 + quad * 8];
                acc2[j] = __builtin_amdgcn_mfma_f32_16x16x32_bf16(wf, pf, acc2[j], 0, 0, 0);
            }
        }
    }
    // epilogue: float4 RMW
    #pragma unroll
    for (int j = 0; j < 8; ++j) {
        float4 bv = *(const float4*)&bias2[j * 16 + quad * 4];
        float* op = out + (size_t)tok * CC + j * 16 + quad * 4;
        float4 cur = *(const float4*)op;
        cur.x += acc2[j][0] + bv.x;
        cur.y += acc2[j][1] + bv.y;
        cur.z += acc2[j][2] + bv.z;
        cur.w += acc2[j][3] + bv.w;
        *(float4*)op = cur;
    }
}

// ============ launch ============
extern "C" void kernel_launch(void* const* d_in, const int* in_sizes, int n_in,
                              void* d_out, int out_size, void* d_ws, size_t ws_size,
                              hipStream_t stream) {
    const float* x       = (const float*)d_in[0];
    const float* norm1_g = (const float*)d_in[1];
    const float* norm1_b = (const float*)d_in[2];
    const float* qkv_w   = (const float*)d_in[3];
    const float* qkv_b   = (const float*)d_in[4];
    const float* rpb     = (const float*)d_in[5];
    const float* proj_w  = (const float*)d_in[6];
    const float* proj_b  = (const float*)d_in[7];
    const float* norm2_g = (const float*)d_in[8];
    const float* norm2_b = (const float*)d_in[9];
    const float* fc1_w   = (const float*)d_in[10];
    const float* fc1_b   = (const float*)d_in[11];
    const float* fc2_w   = (const float*)d_in[12];
    const float* fc2_b   = (const float*)d_in[13];
    const int*   rel_idx = (const int*)d_in[14];

    char* ws = (char*)d_ws;
    float*    biasT = (float*)ws;
    ushort_t* wall  = (ushort_t*)(ws + 65536);
    ushort_t* wqkv  = wall;
    ushort_t* wproj = wall + 49152;
    ushort_t* wfc1  = wall + 65536;
    ushort_t* wfc2  = wall + 131072;
    const size_t base = 524288;
    const size_t szH = (size_t)NTOK * CC * 2;        // 25.7 MB (h2)
    int f = 1;
    while (f < 16) {
        size_t szQ = (size_t)NTOK * 384 * 2 / f;
        size_t szA = (size_t)NTOK * CC * 2 / f;
        if (base + szQ + szA + szH <= ws_size) break;
        f *= 2;
    }
    const size_t szQ = (size_t)NTOK * 384 * 2 / f;
    const size_t szA = (size_t)NTOK * CC * 2 / f;
    int Mc = NTOK / f;
    int wc = NWIN / f;

    ushort_t* Qreg  = (ushort_t*)(ws + base);
    ushort_t* Areg  = (ushort_t*)(ws + base + szQ);
    ushort_t* h2buf = (ushort_t*)(ws + base + szQ + szA);

    prep_weights<<<dim3(768), dim3(256), 0, stream>>>(qkv_w, proj_w, fc1_w, fc2_w, wall);
    build_bias<<<dim3(NHEAD), dim3(256), 0, stream>>>(rpb, rel_idx, biasT);
    for (int c = 0; c < f; ++c) {
        qkv_fused<<<dim3(Mc / 128), dim3(256), 0, stream>>>(
            x, norm1_g, norm1_b, wqkv, qkv_b, Qreg, c * Mc);
        attn_mfma<<<dim3(wc), dim3(256), 0, stream>>>(Qreg, biasT, Areg);
        proj_fused<<<dim3(Mc / 64), dim3(256), 0, stream>>>(
            Areg, wproj, proj_b, x, norm2_g, norm2_b, (float*)d_out, h2buf, c * Mc);
    }
    mlp2<<<dim3(NTOK / 64), dim3(256), 0, stream>>>(
        h2buf, wfc1, fc1_b, wfc2, fc2_b, (float*)d_out);
}

// Round 7
// 360.965 us; speedup vs baseline: 1.4587x; 1.4587x over previous
//
#include <hip/hip_runtime.h>

typedef unsigned short ushort_t;
typedef unsigned int uint_t;

typedef __bf16 bf16x8 __attribute__((ext_vector_type(8)));
typedef float f32x4 __attribute__((ext_vector_type(4)));

static __device__ __forceinline__ float bf2f(ushort_t h) {
    return __uint_as_float(((uint_t)h) << 16);
}
static __device__ __forceinline__ ushort_t f2bf(float f) {
    uint_t u = __float_as_uint(f);
    u = u + 0x7FFFu + ((u >> 16) & 1u);
    return (ushort_t)(u >> 16);
}
// pack two floats as bf16 (round-half-up) into one dword: low=lo, high=hi
static __device__ __forceinline__ uint_t pkbf(float lo, float hi) {
    uint_t a = __float_as_uint(lo) + 0x8000u;
    uint_t b = __float_as_uint(hi) + 0x8000u;
    return __builtin_amdgcn_perm(b, a, 0x07060302u);
}

// ---------------- constants ----------------
#define BB 32
#define HH 56
#define WW_ 56
#define CC 128
#define NHEAD 4
#define WS 7
#define SS 3
#define LL (HH * WW_)           // 3136
#define NTOK (BB * LL)          // 100352
#define NWIN (BB * 64)          // 2048
#define NN 49
#define HD 32

// windowed token -> global token (shift map)
static __device__ __forceinline__ int win2tok(int wid) {
    int win = wid / NN, t = wid - win * NN;
    int bb = win >> 6, wrem = win & 63;
    int wi = wrem >> 3, wj = wrem & 7;
    int ti = t / WS, tj = t - ti * WS;
    int hh = wi * WS + ti + SS; if (hh >= HH) hh -= HH;
    int ww = wj * WS + tj + SS; if (ww >= WW_) ww -= WW_;
    return bb * LL + hh * WW_ + ww;
}

// ============ weight pre-convert fp32->bf16 ============
__global__ __launch_bounds__(256) void prep_weights(
    const float* __restrict__ qkv_w, const float* __restrict__ proj_w,
    const float* __restrict__ fc1_w, const float* __restrict__ fc2_w,
    ushort_t* __restrict__ dst) {
    int i = blockIdx.x * 256 + threadIdx.x;   // 0 .. 196607
    const float* src;
    int off;
    if (i < 49152)        { src = qkv_w;  off = i; }
    else if (i < 65536)   { src = proj_w; off = i - 49152; }
    else if (i < 131072)  { src = fc1_w;  off = i - 65536; }
    else                  { src = fc2_w;  off = i - 131072; }
    dst[i] = f2bf(src[off]);
}

// ============ bias table: bias[h][i][j] (64x64 padded, fp32) ============
__global__ __launch_bounds__(256) void build_bias(
    const float* __restrict__ rpb, const int* __restrict__ rel_idx,
    float* __restrict__ bias) {
    int h = blockIdx.x;
    for (int idx = threadIdx.x; idx < 4096; idx += 256) {
        int i = idx >> 6, j = idx & 63;
        float v = 0.f;
        if (i < NN && j < NN)
            v = rpb[(size_t)rel_idx[i * NN + j] * NHEAD + h];
        bias[h * 4096 + idx] = v;
    }
}

// ============ K1: fused LN1+shift+window + QKV GEMM (r5-verified version) ============
__global__ __launch_bounds__(256) void qkv_fused(
    const float* __restrict__ x, const float* __restrict__ g1,
    const float* __restrict__ b1, const ushort_t* __restrict__ wq,
    const float* __restrict__ qkv_b, ushort_t* __restrict__ qkv,
    int wid0) {
    __shared__ __align__(16) ushort_t As[128 * 136];
    const int tid = threadIdx.x;
    const int m0 = blockIdx.x * 128;
    const int wave = tid >> 6;
    const int lane = tid & 63;
    const int l16 = lane & 15;
    const int quad = lane >> 4;
    const int wm = (wave & 1) * 64;
    const int wn = (wave >> 1) * 64;

    {
        int row = tid >> 1;
        int half = (tid & 1) * 64;
        int gtok = win2tok(wid0 + m0 + row);
        const float* xp = x + (size_t)gtok * CC + half;
        float v[64];
        float s = 0.f, sq = 0.f;
        #pragma unroll
        for (int i = 0; i < 16; ++i) {
            float4 a = *(const float4*)(xp + i * 4);
            v[i * 4 + 0] = a.x; v[i * 4 + 1] = a.y;
            v[i * 4 + 2] = a.z; v[i * 4 + 3] = a.w;
            s += a.x + a.y + a.z + a.w;
            sq += a.x * a.x + a.y * a.y + a.z * a.z + a.w * a.w;
        }
        s += __shfl_xor(s, 1);
        sq += __shfl_xor(sq, 1);
        float mean = s * (1.0f / 128.0f);
        float var = sq * (1.0f / 128.0f) - mean * mean;
        float rstd = rsqrtf(var + 1e-5f);
        #pragma unroll
        for (int i = 0; i < 8; ++i) {
            ushort_t tmp[8];
            #pragma unroll
            for (int j = 0; j < 8; ++j) {
                int c = half + i * 8 + j;
                tmp[j] = f2bf((v[i * 8 + j] - mean) * rstd * g1[c] + b1[c]);
            }
            *(uint4*)&As[row * 136 + half + i * 8] = *(const uint4*)tmp;
        }
    }
    __syncthreads();

    for (int nc = 0; nc < 3; ++nc) {
        f32x4 acc[4][4];
        #pragma unroll
        for (int i = 0; i < 4; ++i)
            #pragma unroll
            for (int j = 0; j < 4; ++j)
                acc[i][j] = (f32x4){0.f, 0.f, 0.f, 0.f};
        #pragma unroll
        for (int kk = 0; kk < 128; kk += 32) {
            bf16x8 af[4], bfr[4];
            #pragma unroll
            for (int i = 0; i < 4; ++i)
                af[i] = *(const bf16x8*)&As[(wm + 16 * i + l16) * 136 + kk + quad * 8];
            #pragma unroll
            for (int j = 0; j < 4; ++j)
                bfr[j] = *(const bf16x8*)&wq[(size_t)(nc * 128 + wn + 16 * j + l16) * 128 + kk + quad * 8];
            #pragma unroll
            for (int i = 0; i < 4; ++i)
                #pragma unroll
                for (int j = 0; j < 4; ++j)
                    acc[i][j] = __builtin_amdgcn_mfma_f32_16x16x32_bf16(af[i], bfr[j], acc[i][j], 0, 0, 0);
        }
        #pragma unroll
        for (int j = 0; j < 4; ++j) {
            int col = nc * 128 + wn + 16 * j + l16;
            float bv = qkv_b[col];
            #pragma unroll
            for (int i = 0; i < 4; ++i)
                #pragma unroll
                for (int r = 0; r < 4; ++r) {
                    int row = m0 + wm + 16 * i + quad * 4 + r;
                    qkv[(size_t)row * 384 + col] = f2bf(acc[i][j][r] + bv);
                }
        }
    }
}

// ============ K2: MFMA windowed attention (verified r3-r6, unchanged) ============
__global__ __launch_bounds__(256) void attn_mfma(
    const ushort_t* __restrict__ qkv, const float* __restrict__ bias,
    ushort_t* __restrict__ attn_out) {
    __shared__ __align__(16) ushort_t Vt[NHEAD][32 * 72];
    __shared__ __align__(16) ushort_t Ps[NHEAD][64 * 72];
    const int tid = threadIdx.x;
    const int wave = tid >> 6;
    const int lane = tid & 63;
    const int l16 = lane & 15;
    const int quad = lane >> 4;
    const int win = blockIdx.x;
    const int h = wave;
    const float scale = 0.17677669529663687f;

    ushort_t* vt = Vt[wave];
    ushort_t* ps = Ps[wave];

    {
        int r0 = lane >> 2;
        int dc = (lane & 3) * 8;
        #pragma unroll
        for (int pass = 0; pass < 4; ++pass) {
            int i = pass * 16 + r0;
            if (i < NN) {
                const ushort_t* src = &qkv[((size_t)(win * NN + i)) * 384 + 256 + h * HD + dc];
                ushort4 a = *(const ushort4*)src;
                ushort4 b = *(const ushort4*)(src + 4);
                vt[(dc + 0) * 72 + i] = a.x; vt[(dc + 1) * 72 + i] = a.y;
                vt[(dc + 2) * 72 + i] = a.z; vt[(dc + 3) * 72 + i] = a.w;
                vt[(dc + 4) * 72 + i] = b.x; vt[(dc + 5) * 72 + i] = b.y;
                vt[(dc + 6) * 72 + i] = b.z; vt[(dc + 7) * 72 + i] = b.w;
            }
        }
        #pragma unroll
        for (int j = 0; j < 8; ++j) {
            int idx = lane * 8 + j;
            if (idx < 32 * 15) {
                int d = idx / 15, n = NN + idx - d * 15;
                vt[d * 72 + n] = 0;
            }
        }
    }

    f32x4 s[4][4];
    {
        bf16x8 qa[4], kb[4];
        #pragma unroll
        for (int t = 0; t < 4; ++t) {
            size_t rb = ((size_t)(win * NN + 16 * t + l16)) * 384 + h * HD + quad * 8;
            qa[t] = *(const bf16x8*)&qkv[rb];
            kb[t] = *(const bf16x8*)&qkv[rb + 128];
        }
        #pragma unroll
        for (int mi = 0; mi < 4; ++mi)
            #pragma unroll
            for (int ni = 0; ni < 4; ++ni) {
                f32x4 z = {0.f, 0.f, 0.f, 0.f};
                s[mi][ni] = __builtin_amdgcn_mfma_f32_16x16x32_bf16(qa[mi], kb[ni], z, 0, 0, 0);
            }
    }

    const float* bh = bias + h * 4096;
    #pragma unroll
    for (int mi = 0; mi < 4; ++mi)
        #pragma unroll
        for (int ni = 0; ni < 4; ++ni)
            #pragma unroll
            for (int r = 0; r < 4; ++r)
                s[mi][ni][r] = s[mi][ni][r] * scale +
                               bh[(16 * mi + quad * 4 + r) * 64 + 16 * ni + l16];

    #pragma unroll
    for (int mi = 0; mi < 4; ++mi)
        #pragma unroll
        for (int r = 0; r < 4; ++r) {
            float m01 = fmaxf(s[mi][0][r], s[mi][1][r]);
            float m2 = s[mi][2][r];
            float m3 = (l16 == 0) ? s[mi][3][r] : -3.0e38f;
            float mx = fmaxf(fmaxf(m01, m2), m3);
            mx = fmaxf(mx, __shfl_xor(mx, 1));
            mx = fmaxf(mx, __shfl_xor(mx, 2));
            mx = fmaxf(mx, __shfl_xor(mx, 4));
            mx = fmaxf(mx, __shfl_xor(mx, 8));
            float e0 = expf(s[mi][0][r] - mx);
            float e1 = expf(s[mi][1][r] - mx);
            float e2 = expf(s[mi][2][r] - mx);
            float e3 = (l16 == 0) ? expf(s[mi][3][r] - mx) : 0.f;
            float sum = (e0 + e1) + (e2 + e3);
            sum += __shfl_xor(sum, 1);
            sum += __shfl_xor(sum, 2);
            sum += __shfl_xor(sum, 4);
            sum += __shfl_xor(sum, 8);
            float inv = 1.0f / sum;
            s[mi][0][r] = e0 * inv;
            s[mi][1][r] = e1 * inv;
            s[mi][2][r] = e2 * inv;
            s[mi][3][r] = e3 * inv;
        }

    #pragma unroll
    for (int mi = 0; mi < 4; ++mi)
        #pragma unroll
        for (int ni = 0; ni < 4; ++ni)
            #pragma unroll
            for (int r = 0; r < 4; ++r)
                ps[(16 * mi + quad * 4 + r) * 72 + 16 * ni + l16] = f2bf(s[mi][ni][r]);

    f32x4 o[2][4];
    #pragma unroll
    for (int it = 0; it < 2; ++it)
        #pragma unroll
        for (int jt = 0; jt < 4; ++jt)
            o[it][jt] = (f32x4){0.f, 0.f, 0.f, 0.f};
    #pragma unroll
    for (int k0 = 0; k0 < 64; k0 += 32) {
        bf16x8 va[2], pb[4];
        #pragma unroll
        for (int it = 0; it < 2; ++it)
            va[it] = *(const bf16x8*)&vt[(16 * it + l16) * 72 + k0 + quad * 8];
        #pragma unroll
        for (int jt = 0; jt < 4; ++jt)
            pb[jt] = *(const bf16x8*)&ps[(16 * jt + l16) * 72 + k0 + quad * 8];
        #pragma unroll
        for (int it = 0; it < 2; ++it)
            #pragma unroll
            for (int jt = 0; jt < 4; ++jt)
                o[it][jt] = __builtin_amdgcn_mfma_f32_16x16x32_bf16(va[it], pb[jt], o[it][jt], 0, 0, 0);
    }

    #pragma unroll
    for (int jt = 0; jt < 4; ++jt) {
        int m = 16 * jt + l16;
        if (m < NN) {
            #pragma unroll
            for (int it = 0; it < 2; ++it) {
                ushort4 st;
                st.x = f2bf(o[it][jt][0]);
                st.y = f2bf(o[it][jt][1]);
                st.z = f2bf(o[it][jt][2]);
                st.w = f2bf(o[it][jt][3]);
                *(ushort4*)&attn_out[((size_t)(win * NN + m)) * CC + h * HD + 16 * it + quad * 4] = st;
            }
        }
    }
}

// ============ K3: fused proj + window-reverse + residual + LN2 + MLP + residual ============
// Block = 64 windowed tokens. Cooperative: wave owns a 32-col slice of each
// weight (1/4 per wave — never broadcast-fetch full matrices, r6 lesson).
// AH buffer: attn staging, then reused for H2. PS: proj^T, then P (fc1 out).
__global__ __launch_bounds__(256) void proj_mlp(
    const ushort_t* __restrict__ attn, const ushort_t* __restrict__ wp,
    const float* __restrict__ proj_b, const float* __restrict__ x,
    const float* __restrict__ g2, const float* __restrict__ b2,
    const ushort_t* __restrict__ w1, const float* __restrict__ b1,
    const ushort_t* __restrict__ w2, const float* __restrict__ bias2,
    float* __restrict__ out, int wid0) {
    __shared__ __align__(16) ushort_t AH[64 * 136];
    __shared__ __align__(16) ushort_t PS[64 * 136];
    const int tid = threadIdx.x;
    const int m0 = blockIdx.x * 64;
    const int wave = tid >> 6;
    const int lane = tid & 63;
    const int l16 = lane & 15;
    const int quad = lane >> 4;
    const int wn = wave * 32;

    // ---- stage attn rows ----
    #pragma unroll
    for (int u = tid; u < 1024; u += 256) {
        int row = u >> 4, ch = (u & 15) * 8;
        *(uint4*)&AH[row * 136 + ch] = *(const uint4*)&attn[(size_t)(m0 + row) * CC + ch];
    }
    __syncthreads();

    // ---- proj MFMA (swapped): D^T[projcol][token] ----
    {
        f32x4 pa[2][4];
        #pragma unroll
        for (int j = 0; j < 2; ++j)
            #pragma unroll
            for (int i = 0; i < 4; ++i)
                pa[j][i] = (f32x4){0.f, 0.f, 0.f, 0.f};
        #pragma unroll
        for (int kk = 0; kk < 4; ++kk) {
            bf16x8 tf[4];
            #pragma unroll
            for (int i = 0; i < 4; ++i)
                tf[i] = *(const bf16x8*)&AH[(16 * i + l16) * 136 + kk * 32 + quad * 8];
            #pragma unroll
            for (int j = 0; j < 2; ++j) {
                bf16x8 wf = *(const bf16x8*)&wp[(size_t)(wn + 16 * j + l16) * 128 + kk * 32 + quad * 8];
                #pragma unroll
                for (int i = 0; i < 4; ++i)
                    pa[j][i] = __builtin_amdgcn_mfma_f32_16x16x32_bf16(wf, tf[i], pa[j][i], 0, 0, 0);
            }
        }
        // PS[token][projcol] via packed b64 stores
        #pragma unroll
        for (int j = 0; j < 2; ++j) {
            float4 bv = *(const float4*)&proj_b[wn + 16 * j + quad * 4];
            #pragma unroll
            for (int i = 0; i < 4; ++i) {
                uint2 pk;
                pk.x = pkbf(pa[j][i][0] + bv.x, pa[j][i][1] + bv.y);
                pk.y = pkbf(pa[j][i][2] + bv.z, pa[j][i][3] + bv.w);
                *(uint2*)&PS[(16 * i + l16) * 136 + wn + 16 * j + quad * 4] = pk;
            }
        }
    }
    __syncthreads();   // PS complete; AH reads complete

    // ---- residual + LN2: x2 -> out (fp32), H2 -> AH (bf16) ----
    {
        int row = tid >> 2;
        int ch0 = (tid & 3) * 32;
        int gtok = win2tok(wid0 + m0 + row);
        const float* xp = x + (size_t)gtok * CC + ch0;
        float v[32];
        float s = 0.f, sq = 0.f;
        #pragma unroll
        for (int i = 0; i < 4; ++i) {
            float4 a0 = *(const float4*)(xp + i * 8);
            float4 a1 = *(const float4*)(xp + i * 8 + 4);
            ushort4 p0 = *(const ushort4*)&PS[row * 136 + ch0 + i * 8];
            ushort4 p1 = *(const ushort4*)&PS[row * 136 + ch0 + i * 8 + 4];
            v[i * 8 + 0] = a0.x + bf2f(p0.x); v[i * 8 + 1] = a0.y + bf2f(p0.y);
            v[i * 8 + 2] = a0.z + bf2f(p0.z); v[i * 8 + 3] = a0.w + bf2f(p0.w);
            v[i * 8 + 4] = a1.x + bf2f(p1.x); v[i * 8 + 5] = a1.y + bf2f(p1.y);
            v[i * 8 + 6] = a1.z + bf2f(p1.z); v[i * 8 + 7] = a1.w + bf2f(p1.w);
            #pragma unroll
            for (int j = 0; j < 8; ++j) { s += v[i * 8 + j]; sq += v[i * 8 + j] * v[i * 8 + j]; }
        }
        float* op = out + (size_t)gtok * CC + ch0;
        #pragma unroll
        for (int i = 0; i < 8; ++i)
            *(float4*)(op + i * 4) = *(const float4*)(v + i * 4);
        s += __shfl_xor(s, 1);  sq += __shfl_xor(sq, 1);
        s += __shfl_xor(s, 2);  sq += __shfl_xor(sq, 2);
        float mean = s * (1.0f / 128.0f);
        float var = sq * (1.0f / 128.0f) - mean * mean;
        float rstd = rsqrtf(var + 1e-5f);
        #pragma unroll
        for (int i = 0; i < 4; ++i) {
            ushort_t tmp[8];
            #pragma unroll
            for (int j = 0; j < 8; ++j) {
                int c = ch0 + i * 8 + j;
                tmp[j] = f2bf((v[i * 8 + j] - mean) * rstd * g2[c] + b2[c]);
            }
            *(uint4*)&AH[row * 136 + ch0 + i * 8] = *(const uint4*)tmp;
        }
    }
    __syncthreads();   // H2 ready; PS proj-reads done

    // ---- MLP: 4 chunks of 128 fc1 cols ----
    f32x4 acc2[2][4];   // [j outColTile][i tokTile]  (swapped MFMA2)
    #pragma unroll
    for (int j = 0; j < 2; ++j)
        #pragma unroll
        for (int i = 0; i < 4; ++i)
            acc2[j][i] = (f32x4){0.f, 0.f, 0.f, 0.f};

    for (int c = 0; c < 4; ++c) {
        // MFMA1 (swapped): D^T[fc1col][token]
        f32x4 s1[2][4];
        #pragma unroll
        for (int j = 0; j < 2; ++j)
            #pragma unroll
            for (int i = 0; i < 4; ++i)
                s1[j][i] = (f32x4){0.f, 0.f, 0.f, 0.f};
        #pragma unroll
        for (int kk = 0; kk < 4; ++kk) {
            bf16x8 tf[4];
            #pragma unroll
            for (int i = 0; i < 4; ++i)
                tf[i] = *(const bf16x8*)&AH[(16 * i + l16) * 136 + kk * 32 + quad * 8];
            #pragma unroll
            for (int j = 0; j < 2; ++j) {
                bf16x8 wf = *(const bf16x8*)&w1[(size_t)(c * 128 + wn + 16 * j + l16) * 128 + kk * 32 + quad * 8];
                #pragma unroll
                for (int i = 0; i < 4; ++i)
                    s1[j][i] = __builtin_amdgcn_mfma_f32_16x16x32_bf16(wf, tf[i], s1[j][i], 0, 0, 0);
            }
        }
        // bias + GELU (sigma form), packed
        uint2 pk[2][4];
        #pragma unroll
        for (int j = 0; j < 2; ++j) {
            float4 bv = *(const float4*)&b1[c * 128 + wn + 16 * j + quad * 4];
            #pragma unroll
            for (int i = 0; i < 4; ++i) {
                float g[4];
                #pragma unroll
                for (int r = 0; r < 4; ++r) {
                    float u = s1[j][i][r] + ((const float*)&bv)[r];
                    float z = 1.5957691216f * u * (1.0f + 0.044715f * u * u);
                    g[r] = u / (1.0f + __expf(-z));
                }
                pk[j][i].x = pkbf(g[0], g[1]);
                pk[j][i].y = pkbf(g[2], g[3]);
            }
        }
        __syncthreads();   // prior PS readers done
        #pragma unroll
        for (int j = 0; j < 2; ++j)
            #pragma unroll
            for (int i = 0; i < 4; ++i)
                *(uint2*)&PS[(16 * i + l16) * 136 + wn + 16 * j + quad * 4] = pk[j][i];
        __syncthreads();   // P ready
        // MFMA2 (swapped): Y^T[outcol][token] += W2c · P^T
        #pragma unroll
        for (int kk = 0; kk < 4; ++kk) {
            bf16x8 pf[4];
            #pragma unroll
            for (int i = 0; i < 4; ++i)
                pf[i] = *(const bf16x8*)&PS[(16 * i + l16) * 136 + kk * 32 + quad * 8];
            #pragma unroll
            for (int j = 0; j < 2; ++j) {
                bf16x8 wf = *(const bf16x8*)&w2[(size_t)(wn + 16 * j + l16) * 512 + c * 128 + kk * 32 + quad * 8];
                #pragma unroll
                for (int i = 0; i < 4; ++i)
                    acc2[j][i] = __builtin_amdgcn_mfma_f32_16x16x32_bf16(wf, pf[i], acc2[j][i], 0, 0, 0);
            }
        }
    }

    // ---- epilogue: float4 RMW on own rows (written in LN2 step, L1/L2-hot) ----
    int gt[4];
    #pragma unroll
    for (int i = 0; i < 4; ++i)
        gt[i] = win2tok(wid0 + m0 + 16 * i + l16);
    #pragma unroll
    for (int j = 0; j < 2; ++j) {
        float4 bv = *(const float4*)&bias2[wn + 16 * j + quad * 4];
        #pragma unroll
        for (int i = 0; i < 4; ++i) {
            float* op = out + (size_t)gt[i] * CC + wn + 16 * j + quad * 4;
            float4 cur = *(const float4*)op;
            cur.x += acc2[j][i][0] + bv.x;
            cur.y += acc2[j][i][1] + bv.y;
            cur.z += acc2[j][i][2] + bv.z;
            cur.w += acc2[j][i][3] + bv.w;
            *(float4*)op = cur;
        }
    }
}

// ============ launch ============
extern "C" void kernel_launch(void* const* d_in, const int* in_sizes, int n_in,
                              void* d_out, int out_size, void* d_ws, size_t ws_size,
                              hipStream_t stream) {
    const float* x       = (const float*)d_in[0];
    const float* norm1_g = (const float*)d_in[1];
    const float* norm1_b = (const float*)d_in[2];
    const float* qkv_w   = (const float*)d_in[3];
    const float* qkv_b   = (const float*)d_in[4];
    const float* rpb     = (const float*)d_in[5];
    const float* proj_w  = (const float*)d_in[6];
    const float* proj_b  = (const float*)d_in[7];
    const float* norm2_g = (const float*)d_in[8];
    const float* norm2_b = (const float*)d_in[9];
    const float* fc1_w   = (const float*)d_in[10];
    const float* fc1_b   = (const float*)d_in[11];
    const float* fc2_w   = (const float*)d_in[12];
    const float* fc2_b   = (const float*)d_in[13];
    const int*   rel_idx = (const int*)d_in[14];

    char* ws = (char*)d_ws;
    float*    biasT = (float*)ws;
    ushort_t* wall  = (ushort_t*)(ws + 65536);
    ushort_t* wqkv  = wall;
    ushort_t* wproj = wall + 49152;
    ushort_t* wfc1  = wall + 65536;
    ushort_t* wfc2  = wall + 131072;
    const size_t base = 524288;
    int f = 1;
    while (f < 16) {
        size_t szQ = (size_t)NTOK * 384 * 2 / f;
        size_t szA = (size_t)NTOK * CC * 2 / f;
        if (base + szQ + szA <= ws_size) break;
        f *= 2;
    }
    const size_t szQ = (size_t)NTOK * 384 * 2 / f;
    int Mc = NTOK / f;
    int wc = NWIN / f;

    ushort_t* Qreg = (ushort_t*)(ws + base);
    ushort_t* Areg = (ushort_t*)(ws + base + szQ);

    prep_weights<<<dim3(768), dim3(256), 0, stream>>>(qkv_w, proj_w, fc1_w, fc2_w, wall);
    build_bias<<<dim3(NHEAD), dim3(256), 0, stream>>>(rpb, rel_idx, biasT);
    for (int c = 0; c < f; ++c) {
        qkv_fused<<<dim3(Mc / 128), dim3(256), 0, stream>>>(
            x, norm1_g, norm1_b, wqkv, qkv_b, Qreg, c * Mc);
        attn_mfma<<<dim3(wc), dim3(256), 0, stream>>>(Qreg, biasT, Areg);
        proj_mlp<<<dim3(Mc / 64), dim3(256), 0, stream>>>(
            Areg, wproj, proj_b, x, norm2_g, norm2_b,
            wfc1, fc1_b, wfc2, fc2_b, (float*)d_out, c * Mc);
    }
}

// Round 8
// 326.942 us; speedup vs baseline: 1.6105x; 1.1041x over previous
//
#include <hip/hip_runtime.h>

typedef unsigned short ushort_t;
typedef unsigned int uint_t;

typedef __bf16 bf16x8 __attribute__((ext_vector_type(8)));
typedef float f32x4 __attribute__((ext_vector_type(4)));

static __device__ __forceinline__ float bf2f(ushort_t h) {
    return __uint_as_float(((uint_t)h) << 16);
}
static __device__ __forceinline__ ushort_t f2bf(float f) {
    uint_t u = __float_as_uint(f);
    u = u + 0x7FFFu + ((u >> 16) & 1u);
    return (ushort_t)(u >> 16);
}
// pack two floats as bf16 (round-half-up) into one dword: low=lo, high=hi
static __device__ __forceinline__ uint_t pkbf(float lo, float hi) {
    uint_t a = __float_as_uint(lo) + 0x8000u;
    uint_t b = __float_as_uint(hi) + 0x8000u;
    return __builtin_amdgcn_perm(b, a, 0x07060302u);
}

// ---------------- constants ----------------
#define BB 32
#define HH 56
#define WW_ 56
#define CC 128
#define NHEAD 4
#define WS 7
#define SS 3
#define LL (HH * WW_)           // 3136
#define NTOK (BB * LL)          // 100352
#define NWIN (BB * 64)          // 2048
#define NN 49
#define HD 32
#define QKS 40                  // Q/K LDS stride (shorts)
#define VTS 72                  // Vt / P LDS stride (shorts)

// windowed token -> global token (shift map)
static __device__ __forceinline__ int win2tok(int wid) {
    int win = wid / NN, t = wid - win * NN;
    int bb = win >> 6, wrem = win & 63;
    int wi = wrem >> 3, wj = wrem & 7;
    int ti = t / WS, tj = t - ti * WS;
    int hh = wi * WS + ti + SS; if (hh >= HH) hh -= HH;
    int ww = wj * WS + tj + SS; if (ww >= WW_) ww -= WW_;
    return bb * LL + hh * WW_ + ww;
}

// ============ weight pre-convert fp32->bf16 ============
__global__ __launch_bounds__(256) void prep_weights(
    const float* __restrict__ qkv_w, const float* __restrict__ proj_w,
    const float* __restrict__ fc1_w, const float* __restrict__ fc2_w,
    ushort_t* __restrict__ dst) {
    int i = blockIdx.x * 256 + threadIdx.x;   // 0 .. 196607
    const float* src;
    int off;
    if (i < 49152)        { src = qkv_w;  off = i; }
    else if (i < 65536)   { src = proj_w; off = i - 49152; }
    else if (i < 131072)  { src = fc1_w;  off = i - 65536; }
    else                  { src = fc2_w;  off = i - 131072; }
    dst[i] = f2bf(src[off]);
}

// ============ bias table: bias[h][i][j] (64x64 padded, fp32) ============
__global__ __launch_bounds__(256) void build_bias(
    const float* __restrict__ rpb, const int* __restrict__ rel_idx,
    float* __restrict__ bias) {
    int h = blockIdx.x;
    for (int idx = threadIdx.x; idx < 4096; idx += 256) {
        int i = idx >> 6, j = idx & 63;
        float v = 0.f;
        if (i < NN && j < NN)
            v = rpb[(size_t)rel_idx[i * NN + j] * NHEAD + h];
        bias[h * 4096 + idx] = v;
    }
}

// ============ K1: fused LN1 + QKV GEMM + windowed attention ============
// Block = 1 window (64 padded tokens), wave = 1 head.
// LN1 -> XLN (cross-wave, single barrier). Per wave: Q,K,V GEMMs with the
// head's 32-col weight slices, token frags cached in regs; Q/K -> LDS
// [token][d] (swapped-MFMA packed stores), V -> LDS [d][token] (non-swapped,
// regs = contiguous tokens). Then S=QK^T, softmax, P -> LDS, O^T = Vt*P^T.
__global__ __launch_bounds__(256) void win_block(
    const float* __restrict__ x, const float* __restrict__ g1,
    const float* __restrict__ b1, const ushort_t* __restrict__ wq,
    const float* __restrict__ qkv_b, const float* __restrict__ bias,
    ushort_t* __restrict__ attn_out, int win0) {
    __shared__ __align__(16) ushort_t XLN[64 * 136];
    __shared__ __align__(16) ushort_t HQK[NHEAD][2 * 64 * QKS];  // Q,K; P overlays
    __shared__ __align__(16) ushort_t HV[NHEAD][32 * VTS];
    const int tid = threadIdx.x;
    const int wave = tid >> 6;          // head
    const int lane = tid & 63;
    const int l16 = lane & 15;
    const int quad = lane >> 4;
    const int h = wave;
    const int win = win0 + blockIdx.x;
    const float scale = 0.17677669529663687f;   // 32^-0.5

    // ---- LN1 (4 threads per row, rows >=49 clamped to token 0) ----
    {
        int row = tid >> 2;
        int ch0 = (tid & 3) * 32;
        int t = (row < NN) ? row : 0;
        int gtok = win2tok(win * NN + t);
        const float* xp = x + (size_t)gtok * CC + ch0;
        float v[32];
        float s = 0.f, sq = 0.f;
        #pragma unroll
        for (int i = 0; i < 4; ++i) {
            float4 a0 = *(const float4*)(xp + i * 8);
            float4 a1 = *(const float4*)(xp + i * 8 + 4);
            v[i * 8 + 0] = a0.x; v[i * 8 + 1] = a0.y;
            v[i * 8 + 2] = a0.z; v[i * 8 + 3] = a0.w;
            v[i * 8 + 4] = a1.x; v[i * 8 + 5] = a1.y;
            v[i * 8 + 6] = a1.z; v[i * 8 + 7] = a1.w;
            #pragma unroll
            for (int j = 0; j < 8; ++j) { s += v[i * 8 + j]; sq += v[i * 8 + j] * v[i * 8 + j]; }
        }
        s += __shfl_xor(s, 1);  sq += __shfl_xor(sq, 1);
        s += __shfl_xor(s, 2);  sq += __shfl_xor(sq, 2);
        float mean = s * (1.0f / 128.0f);
        float var = sq * (1.0f / 128.0f) - mean * mean;
        float rstd = rsqrtf(var + 1e-5f);
        #pragma unroll
        for (int i = 0; i < 4; ++i) {
            ushort_t tmp[8];
            #pragma unroll
            for (int j = 0; j < 8; ++j) {
                int c = ch0 + i * 8 + j;
                tmp[j] = f2bf((v[i * 8 + j] - mean) * rstd * g1[c] + b1[c]);
            }
            *(uint4*)&XLN[row * 136 + ch0 + i * 8] = *(const uint4*)tmp;
        }
    }
    __syncthreads();   // the only barrier

    ushort_t* QL = HQK[h];
    ushort_t* KL = HQK[h] + 64 * QKS;
    ushort_t* PL = HQK[h];            // P overlays Q+K after S is computed
    ushort_t* VT = HV[h];

    // ---- cache token frags (shared A/B frag layout: row l16, k = quad*8+j) ----
    bf16x8 tf[4][4];
    #pragma unroll
    for (int kk = 0; kk < 4; ++kk)
        #pragma unroll
        for (int i = 0; i < 4; ++i)
            tf[kk][i] = *(const bf16x8*)&XLN[(16 * i + l16) * 136 + kk * 32 + quad * 8];

    // ---- Q (swapped: D^T[qcol][token]), scale folded in ----
    {
        f32x4 s1[2][4];
        #pragma unroll
        for (int j = 0; j < 2; ++j)
            #pragma unroll
            for (int i = 0; i < 4; ++i)
                s1[j][i] = (f32x4){0.f, 0.f, 0.f, 0.f};
        #pragma unroll
        for (int kk = 0; kk < 4; ++kk)
            #pragma unroll
            for (int j = 0; j < 2; ++j) {
                bf16x8 wf = *(const bf16x8*)&wq[(size_t)(h * 32 + 16 * j + l16) * 128 + kk * 32 + quad * 8];
                #pragma unroll
                for (int i = 0; i < 4; ++i)
                    s1[j][i] = __builtin_amdgcn_mfma_f32_16x16x32_bf16(wf, tf[kk][i], s1[j][i], 0, 0, 0);
            }
        #pragma unroll
        for (int j = 0; j < 2; ++j) {
            float4 bv = *(const float4*)&qkv_b[h * 32 + 16 * j + quad * 4];
            #pragma unroll
            for (int i = 0; i < 4; ++i) {
                uint2 pk;
                pk.x = pkbf((s1[j][i][0] + bv.x) * scale, (s1[j][i][1] + bv.y) * scale);
                pk.y = pkbf((s1[j][i][2] + bv.z) * scale, (s1[j][i][3] + bv.w) * scale);
                *(uint2*)&QL[(16 * i + l16) * QKS + 16 * j + quad * 4] = pk;
            }
        }
    }
    // ---- K (swapped) ----
    {
        f32x4 s1[2][4];
        #pragma unroll
        for (int j = 0; j < 2; ++j)
            #pragma unroll
            for (int i = 0; i < 4; ++i)
                s1[j][i] = (f32x4){0.f, 0.f, 0.f, 0.f};
        #pragma unroll
        for (int kk = 0; kk < 4; ++kk)
            #pragma unroll
            for (int j = 0; j < 2; ++j) {
                bf16x8 wf = *(const bf16x8*)&wq[(size_t)(128 + h * 32 + 16 * j + l16) * 128 + kk * 32 + quad * 8];
                #pragma unroll
                for (int i = 0; i < 4; ++i)
                    s1[j][i] = __builtin_amdgcn_mfma_f32_16x16x32_bf16(wf, tf[kk][i], s1[j][i], 0, 0, 0);
            }
        #pragma unroll
        for (int j = 0; j < 2; ++j) {
            float4 bv = *(const float4*)&qkv_b[128 + h * 32 + 16 * j + quad * 4];
            #pragma unroll
            for (int i = 0; i < 4; ++i) {
                uint2 pk;
                pk.x = pkbf(s1[j][i][0] + bv.x, s1[j][i][1] + bv.y);
                pk.y = pkbf(s1[j][i][2] + bv.z, s1[j][i][3] + bv.w);
                *(uint2*)&KL[(16 * i + l16) * QKS + 16 * j + quad * 4] = pk;
            }
        }
    }
    // ---- V (non-swapped: D[token][vcol]; regs = contiguous tokens -> Vt[d][token]) ----
    {
        f32x4 sv[4][2];
        #pragma unroll
        for (int i = 0; i < 4; ++i)
            #pragma unroll
            for (int j = 0; j < 2; ++j)
                sv[i][j] = (f32x4){0.f, 0.f, 0.f, 0.f};
        #pragma unroll
        for (int kk = 0; kk < 4; ++kk)
            #pragma unroll
            for (int j = 0; j < 2; ++j) {
                bf16x8 wf = *(const bf16x8*)&wq[(size_t)(256 + h * 32 + 16 * j + l16) * 128 + kk * 32 + quad * 8];
                #pragma unroll
                for (int i = 0; i < 4; ++i)
                    sv[i][j] = __builtin_amdgcn_mfma_f32_16x16x32_bf16(tf[kk][i], wf, sv[i][j], 0, 0, 0);
            }
        #pragma unroll
        for (int j = 0; j < 2; ++j) {
            float bvv = qkv_b[256 + h * 32 + 16 * j + l16];
            #pragma unroll
            for (int i = 0; i < 4; ++i) {
                uint2 pk;
                pk.x = pkbf(sv[i][j][0] + bvv, sv[i][j][1] + bvv);
                pk.y = pkbf(sv[i][j][2] + bvv, sv[i][j][3] + bvv);
                *(uint2*)&VT[(16 * j + l16) * VTS + 16 * i + quad * 4] = pk;
            }
        }
    }

    // ---- S = QK^T (K dim = HD = 32 exactly) ----
    f32x4 s[4][4];
    {
        bf16x8 qa[4], kb[4];
        #pragma unroll
        for (int t = 0; t < 4; ++t) {
            qa[t] = *(const bf16x8*)&QL[(16 * t + l16) * QKS + quad * 8];
            kb[t] = *(const bf16x8*)&KL[(16 * t + l16) * QKS + quad * 8];
        }
        #pragma unroll
        for (int mi = 0; mi < 4; ++mi)
            #pragma unroll
            for (int ni = 0; ni < 4; ++ni) {
                f32x4 z = {0.f, 0.f, 0.f, 0.f};
                s[mi][ni] = __builtin_amdgcn_mfma_f32_16x16x32_bf16(qa[mi], kb[ni], z, 0, 0, 0);
            }
    }

    // ---- + relative-position bias (scale already folded into Q) ----
    const float* bh = bias + h * 4096;
    #pragma unroll
    for (int mi = 0; mi < 4; ++mi)
        #pragma unroll
        for (int ni = 0; ni < 4; ++ni)
            #pragma unroll
            for (int r = 0; r < 4; ++r)
                s[mi][ni][r] += bh[(16 * mi + quad * 4 + r) * 64 + 16 * ni + l16];

    // ---- softmax over cols (cols >=49 masked; verified r3-r7) ----
    #pragma unroll
    for (int mi = 0; mi < 4; ++mi)
        #pragma unroll
        for (int r = 0; r < 4; ++r) {
            float m01 = fmaxf(s[mi][0][r], s[mi][1][r]);
            float m2 = s[mi][2][r];
            float m3 = (l16 == 0) ? s[mi][3][r] : -3.0e38f;
            float mx = fmaxf(fmaxf(m01, m2), m3);
            mx = fmaxf(mx, __shfl_xor(mx, 1));
            mx = fmaxf(mx, __shfl_xor(mx, 2));
            mx = fmaxf(mx, __shfl_xor(mx, 4));
            mx = fmaxf(mx, __shfl_xor(mx, 8));
            float e0 = expf(s[mi][0][r] - mx);
            float e1 = expf(s[mi][1][r] - mx);
            float e2 = expf(s[mi][2][r] - mx);
            float e3 = (l16 == 0) ? expf(s[mi][3][r] - mx) : 0.f;
            float sum = (e0 + e1) + (e2 + e3);
            sum += __shfl_xor(sum, 1);
            sum += __shfl_xor(sum, 2);
            sum += __shfl_xor(sum, 4);
            sum += __shfl_xor(sum, 8);
            float inv = 1.0f / sum;
            s[mi][0][r] = e0 * inv;
            s[mi][1][r] = e1 * inv;
            s[mi][2][r] = e2 * inv;
            s[mi][3][r] = e3 * inv;
        }

    // ---- P -> LDS (overlays Q/K; same-wave ordering, no barrier) ----
    #pragma unroll
    for (int mi = 0; mi < 4; ++mi)
        #pragma unroll
        for (int ni = 0; ni < 4; ++ni)
            #pragma unroll
            for (int r = 0; r < 4; ++r)
                PL[(16 * mi + quad * 4 + r) * VTS + 16 * ni + l16] = f2bf(s[mi][ni][r]);

    // ---- O^T = Vt · P^T ----
    f32x4 o[2][4];
    #pragma unroll
    for (int it = 0; it < 2; ++it)
        #pragma unroll
        for (int jt = 0; jt < 4; ++jt)
            o[it][jt] = (f32x4){0.f, 0.f, 0.f, 0.f};
    #pragma unroll
    for (int k0 = 0; k0 < 64; k0 += 32) {
        bf16x8 va[2], pb[4];
        #pragma unroll
        for (int it = 0; it < 2; ++it)
            va[it] = *(const bf16x8*)&VT[(16 * it + l16) * VTS + k0 + quad * 8];
        #pragma unroll
        for (int jt = 0; jt < 4; ++jt)
            pb[jt] = *(const bf16x8*)&PL[(16 * jt + l16) * VTS + k0 + quad * 8];
        #pragma unroll
        for (int it = 0; it < 2; ++it)
            #pragma unroll
            for (int jt = 0; jt < 4; ++jt)
                o[it][jt] = __builtin_amdgcn_mfma_f32_16x16x32_bf16(va[it], pb[jt], o[it][jt], 0, 0, 0);
    }

    // ---- store O ----
    #pragma unroll
    for (int jt = 0; jt < 4; ++jt) {
        int m = 16 * jt + l16;
        if (m < NN) {
            #pragma unroll
            for (int it = 0; it < 2; ++it) {
                ushort4 st;
                st.x = f2bf(o[it][jt][0]);
                st.y = f2bf(o[it][jt][1]);
                st.z = f2bf(o[it][jt][2]);
                st.w = f2bf(o[it][jt][3]);
                *(ushort4*)&attn_out[((size_t)(blockIdx.x * NN + m)) * CC + h * HD + 16 * it + quad * 4] = st;
            }
        }
    }
}

// ============ K2: fused proj + window-reverse + residual + LN2 + MLP (r7-verified) ============
__global__ __launch_bounds__(256) void proj_mlp(
    const ushort_t* __restrict__ attn, const ushort_t* __restrict__ wp,
    const float* __restrict__ proj_b, const float* __restrict__ x,
    const float* __restrict__ g2, const float* __restrict__ b2,
    const ushort_t* __restrict__ w1, const float* __restrict__ b1,
    const ushort_t* __restrict__ w2, const float* __restrict__ bias2,
    float* __restrict__ out, int wid0) {
    __shared__ __align__(16) ushort_t AH[64 * 136];
    __shared__ __align__(16) ushort_t PS[64 * 136];
    const int tid = threadIdx.x;
    const int m0 = blockIdx.x * 64;
    const int wave = tid >> 6;
    const int lane = tid & 63;
    const int l16 = lane & 15;
    const int quad = lane >> 4;
    const int wn = wave * 32;

    #pragma unroll
    for (int u = tid; u < 1024; u += 256) {
        int row = u >> 4, ch = (u & 15) * 8;
        *(uint4*)&AH[row * 136 + ch] = *(const uint4*)&attn[(size_t)(m0 + row) * CC + ch];
    }
    __syncthreads();

    {
        f32x4 pa[2][4];
        #pragma unroll
        for (int j = 0; j < 2; ++j)
            #pragma unroll
            for (int i = 0; i < 4; ++i)
                pa[j][i] = (f32x4){0.f, 0.f, 0.f, 0.f};
        #pragma unroll
        for (int kk = 0; kk < 4; ++kk) {
            bf16x8 tf[4];
            #pragma unroll
            for (int i = 0; i < 4; ++i)
                tf[i] = *(const bf16x8*)&AH[(16 * i + l16) * 136 + kk * 32 + quad * 8];
            #pragma unroll
            for (int j = 0; j < 2; ++j) {
                bf16x8 wf = *(const bf16x8*)&wp[(size_t)(wn + 16 * j + l16) * 128 + kk * 32 + quad * 8];
                #pragma unroll
                for (int i = 0; i < 4; ++i)
                    pa[j][i] = __builtin_amdgcn_mfma_f32_16x16x32_bf16(wf, tf[i], pa[j][i], 0, 0, 0);
            }
        }
        #pragma unroll
        for (int j = 0; j < 2; ++j) {
            float4 bv = *(const float4*)&proj_b[wn + 16 * j + quad * 4];
            #pragma unroll
            for (int i = 0; i < 4; ++i) {
                uint2 pk;
                pk.x = pkbf(pa[j][i][0] + bv.x, pa[j][i][1] + bv.y);
                pk.y = pkbf(pa[j][i][2] + bv.z, pa[j][i][3] + bv.w);
                *(uint2*)&PS[(16 * i + l16) * 136 + wn + 16 * j + quad * 4] = pk;
            }
        }
    }
    __syncthreads();

    {
        int row = tid >> 2;
        int ch0 = (tid & 3) * 32;
        int gtok = win2tok(wid0 + m0 + row);
        const float* xp = x + (size_t)gtok * CC + ch0;
        float v[32];
        float s = 0.f, sq = 0.f;
        #pragma unroll
        for (int i = 0; i < 4; ++i) {
            float4 a0 = *(const float4*)(xp + i * 8);
            float4 a1 = *(const float4*)(xp + i * 8 + 4);
            ushort4 p0 = *(const ushort4*)&PS[row * 136 + ch0 + i * 8];
            ushort4 p1 = *(const ushort4*)&PS[row * 136 + ch0 + i * 8 + 4];
            v[i * 8 + 0] = a0.x + bf2f(p0.x); v[i * 8 + 1] = a0.y + bf2f(p0.y);
            v[i * 8 + 2] = a0.z + bf2f(p0.z); v[i * 8 + 3] = a0.w + bf2f(p0.w);
            v[i * 8 + 4] = a1.x + bf2f(p1.x); v[i * 8 + 5] = a1.y + bf2f(p1.y);
            v[i * 8 + 6] = a1.z + bf2f(p1.z); v[i * 8 + 7] = a1.w + bf2f(p1.w);
            #pragma unroll
            for (int j = 0; j < 8; ++j) { s += v[i * 8 + j]; sq += v[i * 8 + j] * v[i * 8 + j]; }
        }
        float* op = out + (size_t)gtok * CC + ch0;
        #pragma unroll
        for (int i = 0; i < 8; ++i)
            *(float4*)(op + i * 4) = *(const float4*)(v + i * 4);
        s += __shfl_xor(s, 1);  sq += __shfl_xor(sq, 1);
        s += __shfl_xor(s, 2);  sq += __shfl_xor(sq, 2);
        float mean = s * (1.0f / 128.0f);
        float var = sq * (1.0f / 128.0f) - mean * mean;
        float rstd = rsqrtf(var + 1e-5f);
        #pragma unroll
        for (int i = 0; i < 4; ++i) {
            ushort_t tmp[8];
            #pragma unroll
            for (int j = 0; j < 8; ++j) {
                int c = ch0 + i * 8 + j;
                tmp[j] = f2bf((v[i * 8 + j] - mean) * rstd * g2[c] + b2[c]);
            }
            *(uint4*)&AH[row * 136 + ch0 + i * 8] = *(const uint4*)tmp;
        }
    }
    __syncthreads();

    f32x4 acc2[2][4];
    #pragma unroll
    for (int j = 0; j < 2; ++j)
        #pragma unroll
        for (int i = 0; i < 4; ++i)
            acc2[j][i] = (f32x4){0.f, 0.f, 0.f, 0.f};

    for (int c = 0; c < 4; ++c) {
        f32x4 s1[2][4];
        #pragma unroll
        for (int j = 0; j < 2; ++j)
            #pragma unroll
            for (int i = 0; i < 4; ++i)
                s1[j][i] = (f32x4){0.f, 0.f, 0.f, 0.f};
        #pragma unroll
        for (int kk = 0; kk < 4; ++kk) {
            bf16x8 tf[4];
            #pragma unroll
            for (int i = 0; i < 4; ++i)
                tf[i] = *(const bf16x8*)&AH[(16 * i + l16) * 136 + kk * 32 + quad * 8];
            #pragma unroll
            for (int j = 0; j < 2; ++j) {
                bf16x8 wf = *(const bf16x8*)&w1[(size_t)(c * 128 + wn + 16 * j + l16) * 128 + kk * 32 + quad * 8];
                #pragma unroll
                for (int i = 0; i < 4; ++i)
                    s1[j][i] = __builtin_amdgcn_mfma_f32_16x16x32_bf16(wf, tf[i], s1[j][i], 0, 0, 0);
            }
        }
        uint2 pk[2][4];
        #pragma unroll
        for (int j = 0; j < 2; ++j) {
            float4 bv = *(const float4*)&b1[c * 128 + wn + 16 * j + quad * 4];
            #pragma unroll
            for (int i = 0; i < 4; ++i) {
                float g[4];
                #pragma unroll
                for (int r = 0; r < 4; ++r) {
                    float u = s1[j][i][r] + ((const float*)&bv)[r];
                    float z = 1.5957691216f * u * (1.0f + 0.044715f * u * u);
                    g[r] = u / (1.0f + __expf(-z));
                }
                pk[j][i].x = pkbf(g[0], g[1]);
                pk[j][i].y = pkbf(g[2], g[3]);
            }
        }
        __syncthreads();
        #pragma unroll
        for (int j = 0; j < 2; ++j)
            #pragma unroll
            for (int i = 0; i < 4; ++i)
                *(uint2*)&PS[(16 * i + l16) * 136 + wn + 16 * j + quad * 4] = pk[j][i];
        __syncthreads();
        #pragma unroll
        for (int kk = 0; kk < 4; ++kk) {
            bf16x8 pf[4];
            #pragma unroll
            for (int i = 0; i < 4; ++i)
                pf[i] = *(const bf16x8*)&PS[(16 * i + l16) * 136 + kk * 32 + quad * 8];
            #pragma unroll
            for (int j = 0; j < 2; ++j) {
                bf16x8 wf = *(const bf16x8*)&w2[(size_t)(wn + 16 * j + l16) * 512 + c * 128 + kk * 32 + quad * 8];
                #pragma unroll
                for (int i = 0; i < 4; ++i)
                    acc2[j][i] = __builtin_amdgcn_mfma_f32_16x16x32_bf16(wf, pf[i], acc2[j][i], 0, 0, 0);
            }
        }
    }

    int gt[4];
    #pragma unroll
    for (int i = 0; i < 4; ++i)
        gt[i] = win2tok(wid0 + m0 + 16 * i + l16);
    #pragma unroll
    for (int j = 0; j < 2; ++j) {
        float4 bv = *(const float4*)&bias2[wn + 16 * j + quad * 4];
        #pragma unroll
        for (int i = 0; i < 4; ++i) {
            float* op = out + (size_t)gt[i] * CC + wn + 16 * j + quad * 4;
            float4 cur = *(const float4*)op;
            cur.x += acc2[j][i][0] + bv.x;
            cur.y += acc2[j][i][1] + bv.y;
            cur.z += acc2[j][i][2] + bv.z;
            cur.w += acc2[j][i][3] + bv.w;
            *(float4*)op = cur;
        }
    }
}

// ============ launch ============
extern "C" void kernel_launch(void* const* d_in, const int* in_sizes, int n_in,
                              void* d_out, int out_size, void* d_ws, size_t ws_size,
                              hipStream_t stream) {
    const float* x       = (const float*)d_in[0];
    const float* norm1_g = (const float*)d_in[1];
    const float* norm1_b = (const float*)d_in[2];
    const float* qkv_w   = (const float*)d_in[3];
    const float* qkv_b   = (const float*)d_in[4];
    const float* rpb     = (const float*)d_in[5];
    const float* proj_w  = (const float*)d_in[6];
    const float* proj_b  = (const float*)d_in[7];
    const float* norm2_g = (const float*)d_in[8];
    const float* norm2_b = (const float*)d_in[9];
    const float* fc1_w   = (const float*)d_in[10];
    const float* fc1_b   = (const float*)d_in[11];
    const float* fc2_w   = (const float*)d_in[12];
    const float* fc2_b   = (const float*)d_in[13];
    const int*   rel_idx = (const int*)d_in[14];

    char* ws = (char*)d_ws;
    float*    biasT = (float*)ws;
    ushort_t* wall  = (ushort_t*)(ws + 65536);
    ushort_t* wqkv  = wall;
    ushort_t* wproj = wall + 49152;
    ushort_t* wfc1  = wall + 65536;
    ushort_t* wfc2  = wall + 131072;
    const size_t base = 524288;
    int f = 1;
    while (f < 16) {
        size_t szA = (size_t)NTOK * CC * 2 / f;
        if (base + szA <= ws_size) break;
        f *= 2;
    }
    int Mc = NTOK / f;
    int wc = NWIN / f;

    ushort_t* Areg = (ushort_t*)(ws + base);

    prep_weights<<<dim3(768), dim3(256), 0, stream>>>(qkv_w, proj_w, fc1_w, fc2_w, wall);
    build_bias<<<dim3(NHEAD), dim3(256), 0, stream>>>(rpb, rel_idx, biasT);
    for (int c = 0; c < f; ++c) {
        win_block<<<dim3(wc), dim3(256), 0, stream>>>(
            x, norm1_g, norm1_b, wqkv, qkv_b, biasT, Areg, c * wc);
        proj_mlp<<<dim3(Mc / 64), dim3(256), 0, stream>>>(
            Areg, wproj, proj_b, x, norm2_g, norm2_b,
            wfc1, fc1_b, wfc2, fc2_b, (float*)d_out, c * Mc);
    }
}

// Round 9
// 303.966 us; speedup vs baseline: 1.7323x; 1.0756x over previous
//
#include <hip/hip_runtime.h>

typedef unsigned short ushort_t;
typedef unsigned int uint_t;

typedef __bf16 bf16x8 __attribute__((ext_vector_type(8)));
typedef float f32x4 __attribute__((ext_vector_type(4)));

static __device__ __forceinline__ float bf2f(ushort_t h) {
    return __uint_as_float(((uint_t)h) << 16);
}
static __device__ __forceinline__ ushort_t f2bf(float f) {
    uint_t u = __float_as_uint(f);
    u = u + 0x7FFFu + ((u >> 16) & 1u);
    return (ushort_t)(u >> 16);
}
// pack two floats as bf16 (round-half-up) into one dword: low=lo, high=hi
static __device__ __forceinline__ uint_t pkbf(float lo, float hi) {
    uint_t a = __float_as_uint(lo) + 0x8000u;
    uint_t b = __float_as_uint(hi) + 0x8000u;
    return __builtin_amdgcn_perm(b, a, 0x07060302u);
}

// ---------------- constants ----------------
#define BB 32
#define HH 56
#define WW_ 56
#define CC 128
#define NHEAD 4
#define WS 7
#define SS 3
#define LL (HH * WW_)           // 3136
#define NTOK (BB * LL)          // 100352
#define NWIN (BB * 64)          // 2048
#define NN 49
#define HD 32
#define QKS 32                  // Q/K LDS stride (shorts) — 4-way conflict, cheap
#define PLS 40                  // P half LDS stride (shorts) — conflict-free
#define VTS 72                  // Vt LDS stride (shorts) — conflict-free

// windowed token -> global token (shift map)
static __device__ __forceinline__ int win2tok(int wid) {
    int win = wid / NN, t = wid - win * NN;
    int bb = win >> 6, wrem = win & 63;
    int wi = wrem >> 3, wj = wrem & 7;
    int ti = t / WS, tj = t - ti * WS;
    int hh = wi * WS + ti + SS; if (hh >= HH) hh -= HH;
    int ww = wj * WS + tj + SS; if (ww >= WW_) ww -= WW_;
    return bb * LL + hh * WW_ + ww;
}

// ============ weight pre-convert fp32->bf16 ============
__global__ __launch_bounds__(256) void prep_weights(
    const float* __restrict__ qkv_w, const float* __restrict__ proj_w,
    const float* __restrict__ fc1_w, const float* __restrict__ fc2_w,
    ushort_t* __restrict__ dst) {
    int i = blockIdx.x * 256 + threadIdx.x;   // 0 .. 196607
    const float* src;
    int off;
    if (i < 49152)        { src = qkv_w;  off = i; }
    else if (i < 65536)   { src = proj_w; off = i - 49152; }
    else if (i < 131072)  { src = fc1_w;  off = i - 65536; }
    else                  { src = fc2_w;  off = i - 131072; }
    dst[i] = f2bf(src[off]);
}

// ============ bias table: bias[h][i][j] (64x64 padded, fp32) ============
__global__ __launch_bounds__(256) void build_bias(
    const float* __restrict__ rpb, const int* __restrict__ rel_idx,
    float* __restrict__ bias) {
    int h = blockIdx.x;
    for (int idx = threadIdx.x; idx < 4096; idx += 256) {
        int i = idx >> 6, j = idx & 63;
        float v = 0.f;
        if (i < NN && j < NN)
            v = rpb[(size_t)rel_idx[i * NN + j] * NHEAD + h];
        bias[h * 4096 + idx] = v;
    }
}

// ============ K1: fused LN1 + QKV GEMM + windowed attention ============
// LDS plan (51.2 KB -> 3 blocks/CU):
//   U[16384 shorts]: phase 1 = XLN (64x136); after tf-load barrier, per-head
//   Q (64x32) + K (64x32) slices; after S, P halves (64x40) overlay Q (same
//   wave only, DS-pipe in-order). HV: Vt (4 x 32x72).
__global__ __launch_bounds__(256) void win_block(
    const float* __restrict__ x, const float* __restrict__ g1,
    const float* __restrict__ b1, const ushort_t* __restrict__ wq,
    const float* __restrict__ qkv_b, const float* __restrict__ bias,
    ushort_t* __restrict__ attn_out, int win0) {
    __shared__ __align__(16) ushort_t U[16384];
    __shared__ __align__(16) ushort_t HV[NHEAD][32 * VTS];
    const int tid = threadIdx.x;
    const int wave = tid >> 6;          // head
    const int lane = tid & 63;
    const int l16 = lane & 15;
    const int quad = lane >> 4;
    const int h = wave;
    const int win = win0 + blockIdx.x;
    const float scale = 0.17677669529663687f;   // 32^-0.5

    ushort_t* XLN = U;                         // 64 x 136
    ushort_t* QL = U + h * 4096;               // 64 x 32
    ushort_t* KL = QL + 2048;                  // 64 x 32
    ushort_t* PL = QL;                         // 64 x 40 (overlays Q/K, own wave)
    ushort_t* VT = HV[h];

    // ---- LN1 (4 threads per row, rows >=49 clamped to token 0) ----
    {
        int row = tid >> 2;
        int ch0 = (tid & 3) * 32;
        int t = (row < NN) ? row : 0;
        int gtok = win2tok(win * NN + t);
        const float* xp = x + (size_t)gtok * CC + ch0;
        float v[32];
        float s = 0.f, sq = 0.f;
        #pragma unroll
        for (int i = 0; i < 4; ++i) {
            float4 a0 = *(const float4*)(xp + i * 8);
            float4 a1 = *(const float4*)(xp + i * 8 + 4);
            v[i * 8 + 0] = a0.x; v[i * 8 + 1] = a0.y;
            v[i * 8 + 2] = a0.z; v[i * 8 + 3] = a0.w;
            v[i * 8 + 4] = a1.x; v[i * 8 + 5] = a1.y;
            v[i * 8 + 6] = a1.z; v[i * 8 + 7] = a1.w;
            #pragma unroll
            for (int j = 0; j < 8; ++j) { s += v[i * 8 + j]; sq += v[i * 8 + j] * v[i * 8 + j]; }
        }
        s += __shfl_xor(s, 1);  sq += __shfl_xor(sq, 1);
        s += __shfl_xor(s, 2);  sq += __shfl_xor(sq, 2);
        float mean = s * (1.0f / 128.0f);
        float var = sq * (1.0f / 128.0f) - mean * mean;
        float rstd = rsqrtf(var + 1e-5f);
        #pragma unroll
        for (int i = 0; i < 4; ++i) {
            ushort_t tmp[8];
            #pragma unroll
            for (int j = 0; j < 8; ++j) {
                int c = ch0 + i * 8 + j;
                tmp[j] = f2bf((v[i * 8 + j] - mean) * rstd * g1[c] + b1[c]);
            }
            *(uint4*)&XLN[row * 136 + ch0 + i * 8] = *(const uint4*)tmp;
        }
    }
    __syncthreads();   // XLN ready

    // ---- cache token frags in regs ----
    bf16x8 tf[4][4];
    #pragma unroll
    for (int kk = 0; kk < 4; ++kk)
        #pragma unroll
        for (int i = 0; i < 4; ++i)
            tf[kk][i] = *(const bf16x8*)&XLN[(16 * i + l16) * 136 + kk * 32 + quad * 8];
    __syncthreads();   // XLN dead; U becomes Q/K region

    // ---- Q (swapped: D^T[qcol][token]), scale folded in ----
    {
        f32x4 s1[2][4];
        #pragma unroll
        for (int j = 0; j < 2; ++j)
            #pragma unroll
            for (int i = 0; i < 4; ++i)
                s1[j][i] = (f32x4){0.f, 0.f, 0.f, 0.f};
        #pragma unroll
        for (int kk = 0; kk < 4; ++kk)
            #pragma unroll
            for (int j = 0; j < 2; ++j) {
                bf16x8 wf = *(const bf16x8*)&wq[(size_t)(h * 32 + 16 * j + l16) * 128 + kk * 32 + quad * 8];
                #pragma unroll
                for (int i = 0; i < 4; ++i)
                    s1[j][i] = __builtin_amdgcn_mfma_f32_16x16x32_bf16(wf, tf[kk][i], s1[j][i], 0, 0, 0);
            }
        #pragma unroll
        for (int j = 0; j < 2; ++j) {
            float4 bv = *(const float4*)&qkv_b[h * 32 + 16 * j + quad * 4];
            #pragma unroll
            for (int i = 0; i < 4; ++i) {
                uint2 pk;
                pk.x = pkbf((s1[j][i][0] + bv.x) * scale, (s1[j][i][1] + bv.y) * scale);
                pk.y = pkbf((s1[j][i][2] + bv.z) * scale, (s1[j][i][3] + bv.w) * scale);
                *(uint2*)&QL[(16 * i + l16) * QKS + 16 * j + quad * 4] = pk;
            }
        }
    }
    // ---- K (swapped) ----
    {
        f32x4 s1[2][4];
        #pragma unroll
        for (int j = 0; j < 2; ++j)
            #pragma unroll
            for (int i = 0; i < 4; ++i)
                s1[j][i] = (f32x4){0.f, 0.f, 0.f, 0.f};
        #pragma unroll
        for (int kk = 0; kk < 4; ++kk)
            #pragma unroll
            for (int j = 0; j < 2; ++j) {
                bf16x8 wf = *(const bf16x8*)&wq[(size_t)(128 + h * 32 + 16 * j + l16) * 128 + kk * 32 + quad * 8];
                #pragma unroll
                for (int i = 0; i < 4; ++i)
                    s1[j][i] = __builtin_amdgcn_mfma_f32_16x16x32_bf16(wf, tf[kk][i], s1[j][i], 0, 0, 0);
            }
        #pragma unroll
        for (int j = 0; j < 2; ++j) {
            float4 bv = *(const float4*)&qkv_b[128 + h * 32 + 16 * j + quad * 4];
            #pragma unroll
            for (int i = 0; i < 4; ++i) {
                uint2 pk;
                pk.x = pkbf(s1[j][i][0] + bv.x, s1[j][i][1] + bv.y);
                pk.y = pkbf(s1[j][i][2] + bv.z, s1[j][i][3] + bv.w);
                *(uint2*)&KL[(16 * i + l16) * QKS + 16 * j + quad * 4] = pk;
            }
        }
    }
    // ---- V (non-swapped: D[token][vcol] -> Vt[d][token]) ----
    {
        f32x4 sv[4][2];
        #pragma unroll
        for (int i = 0; i < 4; ++i)
            #pragma unroll
            for (int j = 0; j < 2; ++j)
                sv[i][j] = (f32x4){0.f, 0.f, 0.f, 0.f};
        #pragma unroll
        for (int kk = 0; kk < 4; ++kk)
            #pragma unroll
            for (int j = 0; j < 2; ++j) {
                bf16x8 wf = *(const bf16x8*)&wq[(size_t)(256 + h * 32 + 16 * j + l16) * 128 + kk * 32 + quad * 8];
                #pragma unroll
                for (int i = 0; i < 4; ++i)
                    sv[i][j] = __builtin_amdgcn_mfma_f32_16x16x32_bf16(tf[kk][i], wf, sv[i][j], 0, 0, 0);
            }
        #pragma unroll
        for (int j = 0; j < 2; ++j) {
            float bvv = qkv_b[256 + h * 32 + 16 * j + l16];
            #pragma unroll
            for (int i = 0; i < 4; ++i) {
                uint2 pk;
                pk.x = pkbf(sv[i][j][0] + bvv, sv[i][j][1] + bvv);
                pk.y = pkbf(sv[i][j][2] + bvv, sv[i][j][3] + bvv);
                *(uint2*)&VT[(16 * j + l16) * VTS + 16 * i + quad * 4] = pk;
            }
        }
    }

    // ---- S = QK^T (K dim = HD = 32 exactly) ----
    f32x4 s[4][4];
    {
        bf16x8 qa[4], kb[4];
        #pragma unroll
        for (int t = 0; t < 4; ++t) {
            qa[t] = *(const bf16x8*)&QL[(16 * t + l16) * QKS + quad * 8];
            kb[t] = *(const bf16x8*)&KL[(16 * t + l16) * QKS + quad * 8];
        }
        #pragma unroll
        for (int mi = 0; mi < 4; ++mi)
            #pragma unroll
            for (int ni = 0; ni < 4; ++ni) {
                f32x4 z = {0.f, 0.f, 0.f, 0.f};
                s[mi][ni] = __builtin_amdgcn_mfma_f32_16x16x32_bf16(qa[mi], kb[ni], z, 0, 0, 0);
            }
    }

    // ---- + relative-position bias (scale folded into Q) ----
    const float* bh = bias + h * 4096;
    #pragma unroll
    for (int mi = 0; mi < 4; ++mi)
        #pragma unroll
        for (int ni = 0; ni < 4; ++ni)
            #pragma unroll
            for (int r = 0; r < 4; ++r)
                s[mi][ni][r] += bh[(16 * mi + quad * 4 + r) * 64 + 16 * ni + l16];

    // ---- softmax over cols (cols >=49 masked; verified r3-r8) ----
    #pragma unroll
    for (int mi = 0; mi < 4; ++mi)
        #pragma unroll
        for (int r = 0; r < 4; ++r) {
            float m01 = fmaxf(s[mi][0][r], s[mi][1][r]);
            float m2 = s[mi][2][r];
            float m3 = (l16 == 0) ? s[mi][3][r] : -3.0e38f;
            float mx = fmaxf(fmaxf(m01, m2), m3);
            mx = fmaxf(mx, __shfl_xor(mx, 1));
            mx = fmaxf(mx, __shfl_xor(mx, 2));
            mx = fmaxf(mx, __shfl_xor(mx, 4));
            mx = fmaxf(mx, __shfl_xor(mx, 8));
            float e0 = expf(s[mi][0][r] - mx);
            float e1 = expf(s[mi][1][r] - mx);
            float e2 = expf(s[mi][2][r] - mx);
            float e3 = (l16 == 0) ? expf(s[mi][3][r] - mx) : 0.f;
            float sum = (e0 + e1) + (e2 + e3);
            sum += __shfl_xor(sum, 1);
            sum += __shfl_xor(sum, 2);
            sum += __shfl_xor(sum, 4);
            sum += __shfl_xor(sum, 8);
            float inv = 1.0f / sum;
            s[mi][0][r] = e0 * inv;
            s[mi][1][r] = e1 * inv;
            s[mi][2][r] = e2 * inv;
            s[mi][3][r] = e3 * inv;
        }

    // ---- O^T = Vt · P^T, P streamed in two 32-col halves through PL ----
    f32x4 o[2][4];
    #pragma unroll
    for (int it = 0; it < 2; ++it)
        #pragma unroll
        for (int jt = 0; jt < 4; ++jt)
            o[it][jt] = (f32x4){0.f, 0.f, 0.f, 0.f};
    #pragma unroll
    for (int k0 = 0; k0 < 64; k0 += 32) {
        int nb = k0 >> 4;
        #pragma unroll
        for (int mi = 0; mi < 4; ++mi)
            #pragma unroll
            for (int nn = 0; nn < 2; ++nn)
                #pragma unroll
                for (int r = 0; r < 4; ++r)
                    PL[(16 * mi + quad * 4 + r) * PLS + 16 * nn + l16] = f2bf(s[mi][nb + nn][r]);
        bf16x8 va[2], pb[4];
        #pragma unroll
        for (int it = 0; it < 2; ++it)
            va[it] = *(const bf16x8*)&VT[(16 * it + l16) * VTS + k0 + quad * 8];
        #pragma unroll
        for (int jt = 0; jt < 4; ++jt)
            pb[jt] = *(const bf16x8*)&PL[(16 * jt + l16) * PLS + quad * 8];
        #pragma unroll
        for (int it = 0; it < 2; ++it)
            #pragma unroll
            for (int jt = 0; jt < 4; ++jt)
                o[it][jt] = __builtin_amdgcn_mfma_f32_16x16x32_bf16(va[it], pb[jt], o[it][jt], 0, 0, 0);
    }

    // ---- store O ----
    #pragma unroll
    for (int jt = 0; jt < 4; ++jt) {
        int m = 16 * jt + l16;
        if (m < NN) {
            #pragma unroll
            for (int it = 0; it < 2; ++it) {
                ushort4 st;
                st.x = f2bf(o[it][jt][0]);
                st.y = f2bf(o[it][jt][1]);
                st.z = f2bf(o[it][jt][2]);
                st.w = f2bf(o[it][jt][3]);
                *(ushort4*)&attn_out[((size_t)(blockIdx.x * NN + m)) * CC + h * HD + 16 * it + quad * 4] = st;
            }
        }
    }
}

// ============ K2: fused proj + window-reverse + residual + LN2 + MLP ============
// r8-verified structure + x2 kept in LDS bf16 (no fp32 global write / no RMW).
__global__ __launch_bounds__(256) void proj_mlp(
    const ushort_t* __restrict__ attn, const ushort_t* __restrict__ wp,
    const float* __restrict__ proj_b, const float* __restrict__ x,
    const float* __restrict__ g2, const float* __restrict__ b2,
    const ushort_t* __restrict__ w1, const float* __restrict__ b1,
    const ushort_t* __restrict__ w2, const float* __restrict__ bias2,
    float* __restrict__ out, int wid0) {
    __shared__ __align__(16) ushort_t AH[64 * 136];
    __shared__ __align__(16) ushort_t PS[64 * 136];
    __shared__ __align__(16) ushort_t X2S[64 * 136];
    const int tid = threadIdx.x;
    const int m0 = blockIdx.x * 64;
    const int wave = tid >> 6;
    const int lane = tid & 63;
    const int l16 = lane & 15;
    const int quad = lane >> 4;
    const int wn = wave * 32;

    #pragma unroll
    for (int u = tid; u < 1024; u += 256) {
        int row = u >> 4, ch = (u & 15) * 8;
        *(uint4*)&AH[row * 136 + ch] = *(const uint4*)&attn[(size_t)(m0 + row) * CC + ch];
    }
    __syncthreads();

    {
        f32x4 pa[2][4];
        #pragma unroll
        for (int j = 0; j < 2; ++j)
            #pragma unroll
            for (int i = 0; i < 4; ++i)
                pa[j][i] = (f32x4){0.f, 0.f, 0.f, 0.f};
        #pragma unroll
        for (int kk = 0; kk < 4; ++kk) {
            bf16x8 tf[4];
            #pragma unroll
            for (int i = 0; i < 4; ++i)
                tf[i] = *(const bf16x8*)&AH[(16 * i + l16) * 136 + kk * 32 + quad * 8];
            #pragma unroll
            for (int j = 0; j < 2; ++j) {
                bf16x8 wf = *(const bf16x8*)&wp[(size_t)(wn + 16 * j + l16) * 128 + kk * 32 + quad * 8];
                #pragma unroll
                for (int i = 0; i < 4; ++i)
                    pa[j][i] = __builtin_amdgcn_mfma_f32_16x16x32_bf16(wf, tf[i], pa[j][i], 0, 0, 0);
            }
        }
        #pragma unroll
        for (int j = 0; j < 2; ++j) {
            float4 bv = *(const float4*)&proj_b[wn + 16 * j + quad * 4];
            #pragma unroll
            for (int i = 0; i < 4; ++i) {
                uint2 pk;
                pk.x = pkbf(pa[j][i][0] + bv.x, pa[j][i][1] + bv.y);
                pk.y = pkbf(pa[j][i][2] + bv.z, pa[j][i][3] + bv.w);
                *(uint2*)&PS[(16 * i + l16) * 136 + wn + 16 * j + quad * 4] = pk;
            }
        }
    }
    __syncthreads();

    // ---- residual + LN2: x2 -> X2S (bf16), h2 -> AH (bf16) ----
    {
        int row = tid >> 2;
        int ch0 = (tid & 3) * 32;
        int gtok = win2tok(wid0 + m0 + row);
        const float* xp = x + (size_t)gtok * CC + ch0;
        float v[32];
        float s = 0.f, sq = 0.f;
        #pragma unroll
        for (int i = 0; i < 4; ++i) {
            float4 a0 = *(const float4*)(xp + i * 8);
            float4 a1 = *(const float4*)(xp + i * 8 + 4);
            ushort4 p0 = *(const ushort4*)&PS[row * 136 + ch0 + i * 8];
            ushort4 p1 = *(const ushort4*)&PS[row * 136 + ch0 + i * 8 + 4];
            v[i * 8 + 0] = a0.x + bf2f(p0.x); v[i * 8 + 1] = a0.y + bf2f(p0.y);
            v[i * 8 + 2] = a0.z + bf2f(p0.z); v[i * 8 + 3] = a0.w + bf2f(p0.w);
            v[i * 8 + 4] = a1.x + bf2f(p1.x); v[i * 8 + 5] = a1.y + bf2f(p1.y);
            v[i * 8 + 6] = a1.z + bf2f(p1.z); v[i * 8 + 7] = a1.w + bf2f(p1.w);
            #pragma unroll
            for (int j = 0; j < 8; ++j) { s += v[i * 8 + j]; sq += v[i * 8 + j] * v[i * 8 + j]; }
        }
        #pragma unroll
        for (int i = 0; i < 4; ++i) {
            ushort_t tmp[8];
            #pragma unroll
            for (int j = 0; j < 8; ++j) tmp[j] = f2bf(v[i * 8 + j]);
            *(uint4*)&X2S[row * 136 + ch0 + i * 8] = *(const uint4*)tmp;
        }
        s += __shfl_xor(s, 1);  sq += __shfl_xor(sq, 1);
        s += __shfl_xor(s, 2);  sq += __shfl_xor(sq, 2);
        float mean = s * (1.0f / 128.0f);
        float var = sq * (1.0f / 128.0f) - mean * mean;
        float rstd = rsqrtf(var + 1e-5f);
        #pragma unroll
        for (int i = 0; i < 4; ++i) {
            ushort_t tmp[8];
            #pragma unroll
            for (int j = 0; j < 8; ++j) {
                int c = ch0 + i * 8 + j;
                tmp[j] = f2bf((v[i * 8 + j] - mean) * rstd * g2[c] + b2[c]);
            }
            *(uint4*)&AH[row * 136 + ch0 + i * 8] = *(const uint4*)tmp;
        }
    }
    __syncthreads();

    f32x4 acc2[2][4];
    #pragma unroll
    for (int j = 0; j < 2; ++j)
        #pragma unroll
        for (int i = 0; i < 4; ++i)
            acc2[j][i] = (f32x4){0.f, 0.f, 0.f, 0.f};

    for (int c = 0; c < 4; ++c) {
        f32x4 s1[2][4];
        #pragma unroll
        for (int j = 0; j < 2; ++j)
            #pragma unroll
            for (int i = 0; i < 4; ++i)
                s1[j][i] = (f32x4){0.f, 0.f, 0.f, 0.f};
        #pragma unroll
        for (int kk = 0; kk < 4; ++kk) {
            bf16x8 tf[4];
            #pragma unroll
            for (int i = 0; i < 4; ++i)
                tf[i] = *(const bf16x8*)&AH[(16 * i + l16) * 136 + kk * 32 + quad * 8];
            #pragma unroll
            for (int j = 0; j < 2; ++j) {
                bf16x8 wf = *(const bf16x8*)&w1[(size_t)(c * 128 + wn + 16 * j + l16) * 128 + kk * 32 + quad * 8];
                #pragma unroll
                for (int i = 0; i < 4; ++i)
                    s1[j][i] = __builtin_amdgcn_mfma_f32_16x16x32_bf16(wf, tf[i], s1[j][i], 0, 0, 0);
            }
        }
        uint2 pk[2][4];
        #pragma unroll
        for (int j = 0; j < 2; ++j) {
            float4 bv = *(const float4*)&b1[c * 128 + wn + 16 * j + quad * 4];
            #pragma unroll
            for (int i = 0; i < 4; ++i) {
                float g[4];
                #pragma unroll
                for (int r = 0; r < 4; ++r) {
                    float u = s1[j][i][r] + ((const float*)&bv)[r];
                    float z = 1.5957691216f * u * (1.0f + 0.044715f * u * u);
                    g[r] = u / (1.0f + __expf(-z));
                }
                pk[j][i].x = pkbf(g[0], g[1]);
                pk[j][i].y = pkbf(g[2], g[3]);
            }
        }
        __syncthreads();
        #pragma unroll
        for (int j = 0; j < 2; ++j)
            #pragma unroll
            for (int i = 0; i < 4; ++i)
                *(uint2*)&PS[(16 * i + l16) * 136 + wn + 16 * j + quad * 4] = pk[j][i];
        __syncthreads();
        #pragma unroll
        for (int kk = 0; kk < 4; ++kk) {
            bf16x8 pf[4];
            #pragma unroll
            for (int i = 0; i < 4; ++i)
                pf[i] = *(const bf16x8*)&PS[(16 * i + l16) * 136 + kk * 32 + quad * 8];
            #pragma unroll
            for (int j = 0; j < 2; ++j) {
                bf16x8 wf = *(const bf16x8*)&w2[(size_t)(wn + 16 * j + l16) * 512 + c * 128 + kk * 32 + quad * 8];
                #pragma unroll
                for (int i = 0; i < 4; ++i)
                    acc2[j][i] = __builtin_amdgcn_mfma_f32_16x16x32_bf16(wf, pf[i], acc2[j][i], 0, 0, 0);
            }
        }
    }

    // ---- epilogue: out = x2(LDS) + mlp + bias2, single fp32 write ----
    int gt[4];
    #pragma unroll
    for (int i = 0; i < 4; ++i)
        gt[i] = win2tok(wid0 + m0 + 16 * i + l16);
    #pragma unroll
    for (int j = 0; j < 2; ++j) {
        float4 bv = *(const float4*)&bias2[wn + 16 * j + quad * 4];
        #pragma unroll
        for (int i = 0; i < 4; ++i) {
            ushort4 xv = *(const ushort4*)&X2S[(16 * i + l16) * 136 + wn + 16 * j + quad * 4];
            float4 cur;
            cur.x = bf2f(xv.x) + acc2[j][i][0] + bv.x;
            cur.y = bf2f(xv.y) + acc2[j][i][1] + bv.y;
            cur.z = bf2f(xv.z) + acc2[j][i][2] + bv.z;
            cur.w = bf2f(xv.w) + acc2[j][i][3] + bv.w;
            *(float4*)(out + (size_t)gt[i] * CC + wn + 16 * j + quad * 4) = cur;
        }
    }
}

// ============ launch ============
extern "C" void kernel_launch(void* const* d_in, const int* in_sizes, int n_in,
                              void* d_out, int out_size, void* d_ws, size_t ws_size,
                              hipStream_t stream) {
    const float* x       = (const float*)d_in[0];
    const float* norm1_g = (const float*)d_in[1];
    const float* norm1_b = (const float*)d_in[2];
    const float* qkv_w   = (const float*)d_in[3];
    const float* qkv_b   = (const float*)d_in[4];
    const float* rpb     = (const float*)d_in[5];
    const float* proj_w  = (const float*)d_in[6];
    const float* proj_b  = (const float*)d_in[7];
    const float* norm2_g = (const float*)d_in[8];
    const float* norm2_b = (const float*)d_in[9];
    const float* fc1_w   = (const float*)d_in[10];
    const float* fc1_b   = (const float*)d_in[11];
    const float* fc2_w   = (const float*)d_in[12];
    const float* fc2_b   = (const float*)d_in[13];
    const int*   rel_idx = (const int*)d_in[14];

    char* ws = (char*)d_ws;
    float*    biasT = (float*)ws;
    ushort_t* wall  = (ushort_t*)(ws + 65536);
    ushort_t* wqkv  = wall;
    ushort_t* wproj = wall + 49152;
    ushort_t* wfc1  = wall + 65536;
    ushort_t* wfc2  = wall + 131072;
    const size_t base = 524288;
    int f = 1;
    while (f < 16) {
        size_t szA = (size_t)NTOK * CC * 2 / f;
        if (base + szA <= ws_size) break;
        f *= 2;
    }
    int Mc = NTOK / f;
    int wc = NWIN / f;

    ushort_t* Areg = (ushort_t*)(ws + base);

    prep_weights<<<dim3(768), dim3(256), 0, stream>>>(qkv_w, proj_w, fc1_w, fc2_w, wall);
    build_bias<<<dim3(NHEAD), dim3(256), 0, stream>>>(rpb, rel_idx, biasT);
    for (int c = 0; c < f; ++c) {
        win_block<<<dim3(wc), dim3(256), 0, stream>>>(
            x, norm1_g, norm1_b, wqkv, qkv_b, biasT, Areg, c * wc);
        proj_mlp<<<dim3(Mc / 64), dim3(256), 0, stream>>>(
            Areg, wproj, proj_b, x, norm2_g, norm2_b,
            wfc1, fc1_b, wfc2, fc2_b, (float*)d_out, c * Mc);
    }
}